// Round 8
// baseline (144.201 us; speedup 1.0000x reference)
//
#include <hip/hip_runtime.h>
#include <hip/hip_bf16.h>

typedef __attribute__((ext_vector_type(8))) short bfx8;
typedef __attribute__((ext_vector_type(4))) short bfx4;
typedef __attribute__((ext_vector_type(4))) float fx4;

static __device__ __forceinline__ short f2bf(float f) {
  union { float f; unsigned u; } v; v.f = f;
  unsigned r = v.u + 0x7fffu + ((v.u >> 16) & 1u);
  return (short)(r >> 16);
}

static __device__ __forceinline__ void gld16(const void* g, void* l) {
  __builtin_amdgcn_global_load_lds(
      (const __attribute__((address_space(1))) void*)g,
      (__attribute__((address_space(3))) void*)l, 16, 0, 0);
}

constexpr int Bz = 8, Sq = 512, Em = 1024, Hn = 16, Dh = 64;
constexpr int Mrows = Bz * Sq;             // 4096
constexpr size_t NE = (size_t)Mrows * Em;  // 4,194,304
constexpr size_t WE = (size_t)Em * Em;     // 1,048,576

// ---------------- f32 -> bf16 pre-convert (memory-bound, exact flat grid) ----------------
__global__ __launch_bounds__(256) void convert_kernel(
    const float* __restrict__ q, const float* __restrict__ k,
    const float* __restrict__ v,
    const float* __restrict__ Wq, const float* __restrict__ Wk,
    const float* __restrict__ Wv, const float* __restrict__ Wo,
    short* __restrict__ qx, short* __restrict__ kx, short* __restrict__ vx,
    short* __restrict__ wqb, short* __restrict__ wkb,
    short* __restrict__ wvb, short* __restrict__ wob)
{
  const size_t c = (size_t)blockIdx.x * 256 + threadIdx.x;  // vec8 chunk id
  constexpr size_t CI = NE / 8;   // 524288
  constexpr size_t CW = WE / 8;   // 131072
  const float* src; short* dst; size_t off;
  if (c < 3 * CI) {
    const int sgi = (int)(c / CI);
    src = sgi == 0 ? q : sgi == 1 ? k : v;
    dst = sgi == 0 ? qx : sgi == 1 ? kx : vx;
    off = (c - (size_t)sgi * CI) * 8;
  } else {
    const size_t w = c - 3 * CI;
    const int sgi = (int)(w / CW);
    src = sgi == 0 ? Wq : sgi == 1 ? Wk : sgi == 2 ? Wv : Wo;
    dst = sgi == 0 ? wqb : sgi == 1 ? wkb : sgi == 2 ? wvb : wob;
    off = (w - (size_t)sgi * CW) * 8;
  }
  fx4 a = *(const fx4*)(src + off);
  fx4 b = *(const fx4*)(src + off + 4);
  bfx8 o = { f2bf(a[0]), f2bf(a[1]), f2bf(a[2]), f2bf(a[3]),
             f2bf(b[0]), f2bf(b[1]), f2bf(b[2]), f2bf(b[3]) };
  *(bfx8*)(dst + off) = o;
}

// ---------------- bf16 GEMM, C^T orientation, BK=64 single-buffered ----------------
// (unchanged from R7: XOR both-sides swizzle, LDS-bounce epilogue)
constexpr int LDP = 136;

__global__ __launch_bounds__(256, 4) void gemm_qkv_bf16(
    const short* __restrict__ qx, const short* __restrict__ kx,
    const short* __restrict__ vx,
    const short* __restrict__ Wqb, const short* __restrict__ Wkb,
    const short* __restrict__ Wvb,
    const float* __restrict__ bq, const float* __restrict__ bk,
    const float* __restrict__ bv,
    const float* __restrict__ pos,
    short* __restrict__ qb, short* __restrict__ kb, short* __restrict__ vb)
{
  __shared__ short SM[128 * LDP];
  short* As = SM;            // [128][64]
  short* Bs = SM + 8192;     // [128][64]

  const int z = blockIdx.z;
  const short* X = (z == 0) ? qx : (z == 1) ? kx : vx;
  const short* W = (z == 0) ? Wqb : (z == 1) ? Wkb : Wvb;
  const float* bias = (z == 0) ? bq : (z == 1) ? bk : bv;
  short* dst = (z == 0) ? qb : (z == 1) ? kb : vb;

  const int m0 = blockIdx.x * 128;
  const int n0 = blockIdx.y * 128;
  const int t = threadIdx.x, lane = t & 63, wave = t >> 6;
  const int wr = wave >> 1, wc = wave & 1;
  const int fr = lane & 15, fq = lane >> 4;

  const int trow = t >> 3;
  const int scol = ((t & 7) ^ (trow & 7)) * 8;
  const short* gW = W + (size_t)(n0 + trow) * Em + scol;
  const short* gX = X + (size_t)(m0 + trow) * Em + scol;
  short* lA = As + wave * 512;
  short* lB = Bs + wave * 512;

  const int sw0 = ((fq ^ (fr & 7)) * 8);
  const int sw1 = (((4 + fq) ^ (fr & 7)) * 8);

  fx4 acc[4][4] = {};

  for (int k0 = 0; k0 < Em; k0 += 64) {
#pragma unroll
    for (int r = 0; r < 4; ++r) {
      gld16(gW + (size_t)(32 * r) * Em + k0, lA + r * 2048);
      gld16(gX + (size_t)(32 * r) * Em + k0, lB + r * 2048);
    }
    __syncthreads();

#pragma unroll
    for (int ks = 0; ks < 2; ++ks) {
      const int sw = ks ? sw1 : sw0;
      bfx8 af[4], bf[4];
#pragma unroll
      for (int u = 0; u < 4; ++u)
        af[u] = *(const bfx8*)&As[(wr * 64 + u * 16 + fr) * 64 + sw];
#pragma unroll
      for (int v = 0; v < 4; ++v)
        bf[v] = *(const bfx8*)&Bs[(wc * 64 + v * 16 + fr) * 64 + sw];
#pragma unroll
      for (int u = 0; u < 4; ++u)
#pragma unroll
        for (int v = 0; v < 4; ++v)
          acc[u][v] = __builtin_amdgcn_mfma_f32_16x16x32_bf16(af[u], bf[v], acc[u][v], 0, 0, 0);
    }
    __syncthreads();
  }

  const int rr = t >> 4, jj = t & 15;
  const int b = m0 >> 9;
  if (z < 2) {
#pragma unroll
    for (int u = 0; u < 4; ++u) {
      const int nn = wr * 64 + u * 16 + fq * 4;
      const int nng = n0 + nn;
      const fx4 bb = *(const fx4*)&bias[nng];
#pragma unroll
      for (int v = 0; v < 4; ++v) {
        const int m = wc * 64 + v * 16 + fr;
        const int s = (m0 + m) & (Sq - 1);
        const fx4 pe = *(const fx4*)&pos[(size_t)s * Em + nng];
        const fx4 a = acc[u][v];
        bfx4 o = { f2bf(a[0] + bb[0] + pe[0]), f2bf(a[1] + bb[1] + pe[1]),
                   f2bf(a[2] + bb[2] + pe[2]), f2bf(a[3] + bb[3] + pe[3]) };
        *(bfx4*)&SM[m * LDP + nn] = o;
      }
    }
    __syncthreads();
#pragma unroll
    for (int it = 0; it < 8; ++it) {
      const int m = it * 16 + rr;
      const int s = (m0 + m) & (Sq - 1);
      bfx8 val = *(const bfx8*)&SM[m * LDP + jj * 8];
      const int nng = n0 + jj * 8;
      const int h = nng >> 6, d = nng & 63;
      *(bfx8*)&dst[(((size_t)b * Hn + h) * Sq + s) * Dh + d] = val;
    }
  } else {
#pragma unroll
    for (int u = 0; u < 4; ++u) {
      const int nnb = wr * 64 + u * 16 + fq * 4;
      const int nng = n0 + nnb;
      const fx4 bb = *(const fx4*)&bias[nng];
#pragma unroll
      for (int v = 0; v < 4; ++v) {
        const int m = wc * 64 + v * 16 + fr;
        const int s = (m0 + m) & (Sq - 1);
        const fx4 pe = *(const fx4*)&pos[(size_t)s * Em + nng];
        const fx4 a = acc[u][v];
#pragma unroll
        for (int i = 0; i < 4; ++i) {
          const int row = nnb + i;
          SM[row * LDP + (m ^ ((row & 12) << 2))] = f2bf(a[i] + bb[i] + pe[i]);
        }
      }
    }
    __syncthreads();
    const int s0 = m0 & (Sq - 1);
#pragma unroll
    for (int it = 0; it < 8; ++it) {
      const int row = it * 16 + rr;
      bfx8 val = *(const bfx8*)&SM[row * LDP + ((jj * 8) ^ ((row & 12) << 2))];
      const int nng = n0 + row;
      const int h = nng >> 6, d = nng & 63;
      *(bfx8*)&dst[(((size_t)b * Hn + h) * Dh + d) * Sq + s0 + jj * 8] = val;
    }
  }
}

// output projection: out = wv @ Wo^T + bo  (unchanged from R7)
__global__ __launch_bounds__(256, 4) void gemm_out_bf16(
    const short* __restrict__ wv, const short* __restrict__ Wob,
    const float* __restrict__ bo, float* __restrict__ out)
{
  __shared__ short SM[2 * 8192];
  short* As = SM;
  short* Bs = SM + 8192;

  const int m0 = blockIdx.x * 128;
  const int n0 = blockIdx.y * 128;
  const int t = threadIdx.x, lane = t & 63, wave = t >> 6;
  const int wr = wave >> 1, wc = wave & 1;
  const int fr = lane & 15, fq = lane >> 4;

  const int trow = t >> 3;
  const int scol = ((t & 7) ^ (trow & 7)) * 8;
  const short* gW = Wob + (size_t)(n0 + trow) * Em + scol;
  const short* gX = wv + (size_t)(m0 + trow) * Em + scol;
  short* lA = As + wave * 512;
  short* lB = Bs + wave * 512;

  const int sw0 = ((fq ^ (fr & 7)) * 8);
  const int sw1 = (((4 + fq) ^ (fr & 7)) * 8);

  fx4 acc[4][4] = {};

  for (int k0 = 0; k0 < Em; k0 += 64) {
#pragma unroll
    for (int r = 0; r < 4; ++r) {
      gld16(gW + (size_t)(32 * r) * Em + k0, lA + r * 2048);
      gld16(gX + (size_t)(32 * r) * Em + k0, lB + r * 2048);
    }
    __syncthreads();

#pragma unroll
    for (int ks = 0; ks < 2; ++ks) {
      const int sw = ks ? sw1 : sw0;
      bfx8 af[4], bf[4];
#pragma unroll
      for (int u = 0; u < 4; ++u)
        af[u] = *(const bfx8*)&As[(wr * 64 + u * 16 + fr) * 64 + sw];
#pragma unroll
      for (int v = 0; v < 4; ++v)
        bf[v] = *(const bfx8*)&Bs[(wc * 64 + v * 16 + fr) * 64 + sw];
#pragma unroll
      for (int u = 0; u < 4; ++u)
#pragma unroll
        for (int v = 0; v < 4; ++v)
          acc[u][v] = __builtin_amdgcn_mfma_f32_16x16x32_bf16(af[u], bf[v], acc[u][v], 0, 0, 0);
    }
    __syncthreads();
  }

#pragma unroll
  for (int u = 0; u < 4; ++u) {
    const int nn = n0 + wr * 64 + u * 16 + fq * 4;
    const fx4 bb = *(const fx4*)&bo[nn];
#pragma unroll
    for (int v = 0; v < 4; ++v) {
      const int m = m0 + wc * 64 + v * 16 + fr;
      fx4 val = acc[u][v];
      val[0] += bb[0]; val[1] += bb[1]; val[2] += bb[2]; val[3] += bb[3];
      *(fx4*)&out[(size_t)m * Em + nn] = val;
    }
  }
}

// ---------------- Attention: barrier-free, global->reg K/V (L2-resident) ----------------
// kb [B,H,S,Dh], vb [B,H,Dh,S]: both MFMA B-fragments are 16B-contiguous in
// global. Grid (bh,qt): XCD = (bh + 128*qt) % 8 = bh % 8, so a head's 8
// q-tile blocks share one XCD; per-XCD K+V set = 16 heads x 128KB = 2MB < L2.
// Only LDS use: per-wave P bounce (no __syncthreads anywhere; per-wave DS
// ordering + compiler lgkmcnt handle the RAW/WAR).
constexpr int LDK = 72;

__global__ __launch_bounds__(256) void attn_kernel(
    const short* __restrict__ qb, const short* __restrict__ kb,
    const short* __restrict__ vb, short* __restrict__ wv)
{
  __shared__ short Ps[4][16 * LDK];

  const int bh = blockIdx.x;
  const int qt = blockIdx.y;
  const int t = threadIdx.x, lane = t & 63, wave = t >> 6;
  const int fr = lane & 15, fq = lane >> 4;

  const size_t base = (size_t)bh * Sq * Dh;
  const int q0 = qt * 64 + wave * 16;

  bfx8 qf[2];
  {
    const short* qp = qb + base + (size_t)(q0 + fr) * Dh;
    qf[0] = *(const bfx8*)(qp + fq * 8);
    qf[1] = *(const bfx8*)(qp + 32 + fq * 8);
  }

  // per-lane global bases for K and V^T fragment loads
  const short* kfp = kb + base + (size_t)fr * Dh + fq * 8;        // + (kv0+nf*16)*Dh, +32 for ks=1
  const short* vfp0 = vb + base + (size_t)fr * Sq + fq * 8;       // + (df*16)*Sq + kv0, +32 for ks=1

  float mrow[4] = { -1e30f, -1e30f, -1e30f, -1e30f };
  float lrow[4] = { 0.f, 0.f, 0.f, 0.f };
  fx4 oacc[4] = {};

  for (int kv0 = 0; kv0 < Sq; kv0 += 64) {
    // S = Q K^T : K fragments straight from global (L2-hot)
    fx4 sa[4] = {};
#pragma unroll
    for (int nf = 0; nf < 4; ++nf) {
      const short* kp = kfp + (size_t)(kv0 + nf * 16) * Dh;
      bfx8 kf0 = *(const bfx8*)kp;
      bfx8 kf1 = *(const bfx8*)(kp + 32);
      sa[nf] = __builtin_amdgcn_mfma_f32_16x16x32_bf16(qf[0], kf0, sa[nf], 0, 0, 0);
      sa[nf] = __builtin_amdgcn_mfma_f32_16x16x32_bf16(qf[1], kf1, sa[nf], 0, 0, 0);
    }

    // online softmax; rows of this wave: q = q0 + fq*4 + i
#pragma unroll
    for (int i = 0; i < 4; ++i) {
      float mx = fmaxf(fmaxf(sa[0][i], sa[1][i]), fmaxf(sa[2][i], sa[3][i]));
      mx = fmaxf(mx, __shfl_xor(mx, 1));
      mx = fmaxf(mx, __shfl_xor(mx, 2));
      mx = fmaxf(mx, __shfl_xor(mx, 4));
      mx = fmaxf(mx, __shfl_xor(mx, 8));
      mx *= 0.125f;
      const float mn = fmaxf(mrow[i], mx);
      const float alpha = __expf(mrow[i] - mn);
      mrow[i] = mn;
      float rs = 0.f;
#pragma unroll
      for (int nf = 0; nf < 4; ++nf) {
        const float p = __expf(sa[nf][i] * 0.125f - mn);
        rs += p;
        Ps[wave][(fq * 4 + i) * LDK + nf * 16 + fr] = f2bf(p);
      }
      rs += __shfl_xor(rs, 1);
      rs += __shfl_xor(rs, 2);
      rs += __shfl_xor(rs, 4);
      rs += __shfl_xor(rs, 8);
      lrow[i] = lrow[i] * alpha + rs;
#pragma unroll
      for (int df = 0; df < 4; ++df) oacc[df][i] *= alpha;
    }

    // O += P @ V : P bounced through per-wave LDS (no barrier needed),
    // V^T fragments straight from global (L2-hot)
    bfx8 pf[2];
    pf[0] = *(const bfx8*)&Ps[wave][fr * LDK + fq * 8];
    pf[1] = *(const bfx8*)&Ps[wave][fr * LDK + 32 + fq * 8];
#pragma unroll
    for (int df = 0; df < 4; ++df) {
      const short* vp = vfp0 + (size_t)(df * 16) * Sq + kv0;
      bfx8 vf0 = *(const bfx8*)vp;
      bfx8 vf1 = *(const bfx8*)(vp + 32);
      oacc[df] = __builtin_amdgcn_mfma_f32_16x16x32_bf16(pf[0], vf0, oacc[df], 0, 0, 0);
      oacc[df] = __builtin_amdgcn_mfma_f32_16x16x32_bf16(pf[1], vf1, oacc[df], 0, 0, 0);
    }
  }

  const int b = bh >> 4, h = bh & 15;
#pragma unroll
  for (int df = 0; df < 4; ++df) {
    const int d = df * 16 + fr;
#pragma unroll
    for (int i = 0; i < 4; ++i) {
      const int qrow = q0 + fq * 4 + i;
      const float o = oacc[df][i] / lrow[i];
      wv[((size_t)b * Sq + qrow) * Em + h * Dh + d] = f2bf(o);
    }
  }
}

extern "C" void kernel_launch(void* const* d_in, const int* in_sizes, int n_in,
                              void* d_out, int out_size, void* d_ws, size_t ws_size,
                              hipStream_t stream) {
  (void)in_sizes; (void)n_in; (void)out_size; (void)ws_size;
  const float* query = (const float*)d_in[0];
  const float* key   = (const float*)d_in[1];
  const float* value = (const float*)d_in[2];
  const float* Wq = (const float*)d_in[3];
  const float* bq = (const float*)d_in[4];
  const float* Wk = (const float*)d_in[5];
  const float* bk = (const float*)d_in[6];
  const float* Wv = (const float*)d_in[7];
  const float* bv = (const float*)d_in[8];
  const float* Wo = (const float*)d_in[9];
  const float* bo = (const float*)d_in[10];
  const float* pos = (const float*)d_in[11];

  short* qx = (short*)d_ws;
  short* kx = qx + NE;
  short* vx = kx + NE;
  short* Wqb = vx + NE;
  short* Wkb = Wqb + WE;
  short* Wvb = Wkb + WE;
  short* Wob = Wvb + WE;
  short* qb = Wob + WE;
  short* wv = qx;                 // alias: qx dead after gemm_qkv
  short* kb = (short*)d_out;      // d_out scratch, overwritten by gemm_out
  short* vb = kb + NE;            // [B,H,Dh,S]

  convert_kernel<<<dim3(8192), 256, 0, stream>>>(
      query, key, value, Wq, Wk, Wv, Wo, qx, kx, vx, Wqb, Wkb, Wvb, Wob);
  gemm_qkv_bf16<<<dim3(Mrows / 128, Em / 128, 3), 256, 0, stream>>>(
      qx, kx, vx, Wqb, Wkb, Wvb, bq, bk, bv, pos, qb, kb, vb);
  attn_kernel<<<dim3(Bz * Hn, Sq / 64), 256, 0, stream>>>(qb, kb, vb, wv);
  gemm_out_bf16<<<dim3(Mrows / 128, Em / 128), 256, 0, stream>>>(
      wv, Wob, bo, (float*)d_out);
}

// Round 9
// 115.673 us; speedup vs baseline: 1.2466x; 1.2466x over previous
//
#include <hip/hip_runtime.h>
#include <hip/hip_bf16.h>

typedef __attribute__((ext_vector_type(8))) short bfx8;
typedef __attribute__((ext_vector_type(4))) short bfx4;
typedef __attribute__((ext_vector_type(4))) float fx4;

static __device__ __forceinline__ short f2bf(float f) {
  union { float f; unsigned u; } v; v.f = f;
  unsigned r = v.u + 0x7fffu + ((v.u >> 16) & 1u);
  return (short)(r >> 16);
}

static __device__ __forceinline__ void gld16(const void* g, void* l) {
  __builtin_amdgcn_global_load_lds(
      (const __attribute__((address_space(1))) void*)g,
      (__attribute__((address_space(3))) void*)l, 16, 0, 0);
}

constexpr int Bz = 8, Sq = 512, Em = 1024, Hn = 16, Dh = 64;
constexpr int Mrows = Bz * Sq;             // 4096
constexpr size_t NE = (size_t)Mrows * Em;  // 4,194,304
constexpr size_t WE = (size_t)Em * Em;     // 1,048,576

// ---------------- f32 -> bf16 pre-convert (memory-bound, exact flat grid) ----------------
__global__ __launch_bounds__(256) void convert_kernel(
    const float* __restrict__ q, const float* __restrict__ k,
    const float* __restrict__ v,
    const float* __restrict__ Wq, const float* __restrict__ Wk,
    const float* __restrict__ Wv, const float* __restrict__ Wo,
    short* __restrict__ qx, short* __restrict__ kx, short* __restrict__ vx,
    short* __restrict__ wqb, short* __restrict__ wkb,
    short* __restrict__ wvb, short* __restrict__ wob)
{
  const size_t c = (size_t)blockIdx.x * 256 + threadIdx.x;  // vec8 chunk id
  constexpr size_t CI = NE / 8;   // 524288
  constexpr size_t CW = WE / 8;   // 131072
  const float* src; short* dst; size_t off;
  if (c < 3 * CI) {
    const int sgi = (int)(c / CI);
    src = sgi == 0 ? q : sgi == 1 ? k : v;
    dst = sgi == 0 ? qx : sgi == 1 ? kx : vx;
    off = (c - (size_t)sgi * CI) * 8;
  } else {
    const size_t w = c - 3 * CI;
    const int sgi = (int)(w / CW);
    src = sgi == 0 ? Wq : sgi == 1 ? Wk : sgi == 2 ? Wv : Wo;
    dst = sgi == 0 ? wqb : sgi == 1 ? wkb : sgi == 2 ? wvb : wob;
    off = (w - (size_t)sgi * CW) * 8;
  }
  fx4 a = *(const fx4*)(src + off);
  fx4 b = *(const fx4*)(src + off + 4);
  bfx8 o = { f2bf(a[0]), f2bf(a[1]), f2bf(a[2]), f2bf(a[3]),
             f2bf(b[0]), f2bf(b[1]), f2bf(b[2]), f2bf(b[3]) };
  *(bfx8*)(dst + off) = o;
}

// ---------------- bf16 GEMM, C^T orientation, BK=64 single-buffered ----------------
// (unchanged from R7: XOR both-sides swizzle, LDS-bounce epilogue)
constexpr int LDP = 136;

__global__ __launch_bounds__(256, 4) void gemm_qkv_bf16(
    const short* __restrict__ qx, const short* __restrict__ kx,
    const short* __restrict__ vx,
    const short* __restrict__ Wqb, const short* __restrict__ Wkb,
    const short* __restrict__ Wvb,
    const float* __restrict__ bq, const float* __restrict__ bk,
    const float* __restrict__ bv,
    const float* __restrict__ pos,
    short* __restrict__ qb, short* __restrict__ kb, short* __restrict__ vb)
{
  __shared__ short SM[128 * LDP];
  short* As = SM;            // [128][64]
  short* Bs = SM + 8192;     // [128][64]

  const int z = blockIdx.z;
  const short* X = (z == 0) ? qx : (z == 1) ? kx : vx;
  const short* W = (z == 0) ? Wqb : (z == 1) ? Wkb : Wvb;
  const float* bias = (z == 0) ? bq : (z == 1) ? bk : bv;
  short* dst = (z == 0) ? qb : (z == 1) ? kb : vb;

  const int m0 = blockIdx.x * 128;
  const int n0 = blockIdx.y * 128;
  const int t = threadIdx.x, lane = t & 63, wave = t >> 6;
  const int wr = wave >> 1, wc = wave & 1;
  const int fr = lane & 15, fq = lane >> 4;

  const int trow = t >> 3;
  const int scol = ((t & 7) ^ (trow & 7)) * 8;
  const short* gW = W + (size_t)(n0 + trow) * Em + scol;
  const short* gX = X + (size_t)(m0 + trow) * Em + scol;
  short* lA = As + wave * 512;
  short* lB = Bs + wave * 512;

  const int sw0 = ((fq ^ (fr & 7)) * 8);
  const int sw1 = (((4 + fq) ^ (fr & 7)) * 8);

  fx4 acc[4][4] = {};

  for (int k0 = 0; k0 < Em; k0 += 64) {
#pragma unroll
    for (int r = 0; r < 4; ++r) {
      gld16(gW + (size_t)(32 * r) * Em + k0, lA + r * 2048);
      gld16(gX + (size_t)(32 * r) * Em + k0, lB + r * 2048);
    }
    __syncthreads();

#pragma unroll
    for (int ks = 0; ks < 2; ++ks) {
      const int sw = ks ? sw1 : sw0;
      bfx8 af[4], bf[4];
#pragma unroll
      for (int u = 0; u < 4; ++u)
        af[u] = *(const bfx8*)&As[(wr * 64 + u * 16 + fr) * 64 + sw];
#pragma unroll
      for (int v = 0; v < 4; ++v)
        bf[v] = *(const bfx8*)&Bs[(wc * 64 + v * 16 + fr) * 64 + sw];
#pragma unroll
      for (int u = 0; u < 4; ++u)
#pragma unroll
        for (int v = 0; v < 4; ++v)
          acc[u][v] = __builtin_amdgcn_mfma_f32_16x16x32_bf16(af[u], bf[v], acc[u][v], 0, 0, 0);
    }
    __syncthreads();
  }

  const int rr = t >> 4, jj = t & 15;
  const int b = m0 >> 9;
  if (z < 2) {
#pragma unroll
    for (int u = 0; u < 4; ++u) {
      const int nn = wr * 64 + u * 16 + fq * 4;
      const int nng = n0 + nn;
      const fx4 bb = *(const fx4*)&bias[nng];
#pragma unroll
      for (int v = 0; v < 4; ++v) {
        const int m = wc * 64 + v * 16 + fr;
        const int s = (m0 + m) & (Sq - 1);
        const fx4 pe = *(const fx4*)&pos[(size_t)s * Em + nng];
        const fx4 a = acc[u][v];
        bfx4 o = { f2bf(a[0] + bb[0] + pe[0]), f2bf(a[1] + bb[1] + pe[1]),
                   f2bf(a[2] + bb[2] + pe[2]), f2bf(a[3] + bb[3] + pe[3]) };
        *(bfx4*)&SM[m * LDP + nn] = o;
      }
    }
    __syncthreads();
#pragma unroll
    for (int it = 0; it < 8; ++it) {
      const int m = it * 16 + rr;
      const int s = (m0 + m) & (Sq - 1);
      bfx8 val = *(const bfx8*)&SM[m * LDP + jj * 8];
      const int nng = n0 + jj * 8;
      const int h = nng >> 6, d = nng & 63;
      *(bfx8*)&dst[(((size_t)b * Hn + h) * Sq + s) * Dh + d] = val;
    }
  } else {
#pragma unroll
    for (int u = 0; u < 4; ++u) {
      const int nnb = wr * 64 + u * 16 + fq * 4;
      const int nng = n0 + nnb;
      const fx4 bb = *(const fx4*)&bias[nng];
#pragma unroll
      for (int v = 0; v < 4; ++v) {
        const int m = wc * 64 + v * 16 + fr;
        const int s = (m0 + m) & (Sq - 1);
        const fx4 pe = *(const fx4*)&pos[(size_t)s * Em + nng];
        const fx4 a = acc[u][v];
#pragma unroll
        for (int i = 0; i < 4; ++i) {
          const int row = nnb + i;
          SM[row * LDP + (m ^ ((row & 12) << 2))] = f2bf(a[i] + bb[i] + pe[i]);
        }
      }
    }
    __syncthreads();
    const int s0 = m0 & (Sq - 1);
#pragma unroll
    for (int it = 0; it < 8; ++it) {
      const int row = it * 16 + rr;
      bfx8 val = *(const bfx8*)&SM[row * LDP + ((jj * 8) ^ ((row & 12) << 2))];
      const int nng = n0 + row;
      const int h = nng >> 6, d = nng & 63;
      *(bfx8*)&dst[(((size_t)b * Hn + h) * Dh + d) * Sq + s0 + jj * 8] = val;
    }
  }
}

// output projection: out = wv @ Wo^T + bo  (unchanged from R7)
__global__ __launch_bounds__(256, 4) void gemm_out_bf16(
    const short* __restrict__ wv, const short* __restrict__ Wob,
    const float* __restrict__ bo, float* __restrict__ out)
{
  __shared__ short SM[2 * 8192];
  short* As = SM;
  short* Bs = SM + 8192;

  const int m0 = blockIdx.x * 128;
  const int n0 = blockIdx.y * 128;
  const int t = threadIdx.x, lane = t & 63, wave = t >> 6;
  const int wr = wave >> 1, wc = wave & 1;
  const int fr = lane & 15, fq = lane >> 4;

  const int trow = t >> 3;
  const int scol = ((t & 7) ^ (trow & 7)) * 8;
  const short* gW = Wob + (size_t)(n0 + trow) * Em + scol;
  const short* gX = wv + (size_t)(m0 + trow) * Em + scol;
  short* lA = As + wave * 512;
  short* lB = Bs + wave * 512;

  const int sw0 = ((fq ^ (fr & 7)) * 8);
  const int sw1 = (((4 + fq) ^ (fr & 7)) * 8);

  fx4 acc[4][4] = {};

  for (int k0 = 0; k0 < Em; k0 += 64) {
#pragma unroll
    for (int r = 0; r < 4; ++r) {
      gld16(gW + (size_t)(32 * r) * Em + k0, lA + r * 2048);
      gld16(gX + (size_t)(32 * r) * Em + k0, lB + r * 2048);
    }
    __syncthreads();

#pragma unroll
    for (int ks = 0; ks < 2; ++ks) {
      const int sw = ks ? sw1 : sw0;
      bfx8 af[4], bf[4];
#pragma unroll
      for (int u = 0; u < 4; ++u)
        af[u] = *(const bfx8*)&As[(wr * 64 + u * 16 + fr) * 64 + sw];
#pragma unroll
      for (int v = 0; v < 4; ++v)
        bf[v] = *(const bfx8*)&Bs[(wc * 64 + v * 16 + fr) * 64 + sw];
#pragma unroll
      for (int u = 0; u < 4; ++u)
#pragma unroll
        for (int v = 0; v < 4; ++v)
          acc[u][v] = __builtin_amdgcn_mfma_f32_16x16x32_bf16(af[u], bf[v], acc[u][v], 0, 0, 0);
    }
    __syncthreads();
  }

#pragma unroll
  for (int u = 0; u < 4; ++u) {
    const int nn = n0 + wr * 64 + u * 16 + fq * 4;
    const fx4 bb = *(const fx4*)&bo[nn];
#pragma unroll
    for (int v = 0; v < 4; ++v) {
      const int m = m0 + wc * 64 + v * 16 + fr;
      fx4 val = acc[u][v];
      val[0] += bb[0]; val[1] += bb[1]; val[2] += bb[2]; val[3] += bb[3];
      *(fx4*)&out[(size_t)m * Em + nn] = val;
    }
  }
}

// ---------------- Attention: LDS-staged (R7) + T14 async-STAGE split ----------------
// kb [B,H,S,Dh], vb [B,H,Dh,S]. Next tile's K/V issued into REGISTERS before
// the current tile's compute (QK^T+softmax+PV hides the ~200-500cy load
// latency); LDS write happens after the read-barrier. Same 2-barrier skeleton
// as R7 (no new race surface). Per-wave Ps RAW needs no barrier (R8-proven).
constexpr int KVB = 64, LDK = 72;

__global__ __launch_bounds__(256) void attn_kernel(
    const short* __restrict__ qb, const short* __restrict__ kb,
    const short* __restrict__ vb, short* __restrict__ wv)
{
  __shared__ short Ks[KVB * LDK];   // K tile [kv][d]
  __shared__ short Vt[Dh * LDK];    // V^T tile [d][kv]
  __shared__ short Ps[4][16 * LDK];

  const int bh = blockIdx.x;
  const int qt = blockIdx.y;
  const int t = threadIdx.x, lane = t & 63, wave = t >> 6;
  const int fr = lane & 15, fq = lane >> 4;

  const size_t base = (size_t)bh * Sq * Dh;
  const int q0 = qt * 64 + wave * 16;

  bfx8 qf[2];
  {
    const short* qp = qb + base + (size_t)(q0 + fr) * Dh;
    qf[0] = *(const bfx8*)(qp + fq * 8);
    qf[1] = *(const bfx8*)(qp + 32 + fq * 8);
  }

  // staging coords: thread t -> K row kr, cols [kc,kc+16); V^T row kr (=d),
  // cols [kc,kc+16) of the kv axis
  const int kr = t >> 2, kc = (t & 3) * 16;
  const short* kbp = kb + base + (size_t)kr * Dh + kc;   // + kv0*Dh
  const short* vbp = vb + base + (size_t)kr * Sq + kc;   // + kv0

  // prologue: stage tile 0
  {
    bfx8 k0 = *(const bfx8*)kbp;
    bfx8 k1 = *(const bfx8*)(kbp + 8);
    bfx8 v0 = *(const bfx8*)vbp;
    bfx8 v1 = *(const bfx8*)(vbp + 8);
    *(bfx8*)&Ks[kr * LDK + kc] = k0;
    *(bfx8*)&Ks[kr * LDK + kc + 8] = k1;
    *(bfx8*)&Vt[kr * LDK + kc] = v0;
    *(bfx8*)&Vt[kr * LDK + kc + 8] = v1;
  }
  __syncthreads();

  float mrow[4] = { -1e30f, -1e30f, -1e30f, -1e30f };
  float lrow[4] = { 0.f, 0.f, 0.f, 0.f };
  fx4 oacc[4] = {};

  for (int kv0 = 0; kv0 < Sq; kv0 += KVB) {
    const bool more = (kv0 + KVB) < Sq;
    // T14: issue next tile's global loads NOW; latency hides under compute
    bfx8 nk0, nk1, nv0, nv1;
    if (more) {
      const short* nk = kbp + (size_t)(kv0 + KVB) * Dh;
      const short* nv = vbp + (kv0 + KVB);
      nk0 = *(const bfx8*)nk;
      nk1 = *(const bfx8*)(nk + 8);
      nv0 = *(const bfx8*)nv;
      nv1 = *(const bfx8*)(nv + 8);
    }

    // S = Q K^T
    fx4 sa[4] = {};
#pragma unroll
    for (int nf = 0; nf < 4; ++nf) {
#pragma unroll
      for (int ks = 0; ks < 2; ++ks) {
        bfx8 kf = *(const bfx8*)&Ks[(nf * 16 + fr) * LDK + ks * 32 + fq * 8];
        sa[nf] = __builtin_amdgcn_mfma_f32_16x16x32_bf16(qf[ks], kf, sa[nf], 0, 0, 0);
      }
    }

    // online softmax; rows of this wave: q = q0 + fq*4 + i
#pragma unroll
    for (int i = 0; i < 4; ++i) {
      float mx = fmaxf(fmaxf(sa[0][i], sa[1][i]), fmaxf(sa[2][i], sa[3][i]));
      mx = fmaxf(mx, __shfl_xor(mx, 1));
      mx = fmaxf(mx, __shfl_xor(mx, 2));
      mx = fmaxf(mx, __shfl_xor(mx, 4));
      mx = fmaxf(mx, __shfl_xor(mx, 8));
      mx *= 0.125f;
      const float mn = fmaxf(mrow[i], mx);
      const float alpha = __expf(mrow[i] - mn);
      mrow[i] = mn;
      float rs = 0.f;
#pragma unroll
      for (int nf = 0; nf < 4; ++nf) {
        const float p = __expf(sa[nf][i] * 0.125f - mn);
        rs += p;
        Ps[wave][(fq * 4 + i) * LDK + nf * 16 + fr] = f2bf(p);
      }
      rs += __shfl_xor(rs, 1);
      rs += __shfl_xor(rs, 2);
      rs += __shfl_xor(rs, 4);
      rs += __shfl_xor(rs, 8);
      lrow[i] = lrow[i] * alpha + rs;
#pragma unroll
      for (int df = 0; df < 4; ++df) oacc[df][i] *= alpha;
    }

    // O += P @ V (per-wave Ps RAW: compiler lgkmcnt, no barrier needed)
    bfx8 pf[2];
    pf[0] = *(const bfx8*)&Ps[wave][fr * LDK + fq * 8];
    pf[1] = *(const bfx8*)&Ps[wave][fr * LDK + 32 + fq * 8];
#pragma unroll
    for (int df = 0; df < 4; ++df) {
#pragma unroll
      for (int ks = 0; ks < 2; ++ks) {
        bfx8 vf = *(const bfx8*)&Vt[(df * 16 + fr) * LDK + ks * 32 + fq * 8];
        oacc[df] = __builtin_amdgcn_mfma_f32_16x16x32_bf16(pf[ks], vf, oacc[df], 0, 0, 0);
      }
    }
    __syncthreads();   // all waves done reading Ks/Vt

    if (more) {        // write prefetched tile to LDS
      *(bfx8*)&Ks[kr * LDK + kc] = nk0;
      *(bfx8*)&Ks[kr * LDK + kc + 8] = nk1;
      *(bfx8*)&Vt[kr * LDK + kc] = nv0;
      *(bfx8*)&Vt[kr * LDK + kc + 8] = nv1;
      __syncthreads(); // tile ready
    }
  }

  const int b = bh >> 4, h = bh & 15;
#pragma unroll
  for (int df = 0; df < 4; ++df) {
    const int d = df * 16 + fr;
#pragma unroll
    for (int i = 0; i < 4; ++i) {
      const int qrow = q0 + fq * 4 + i;
      const float o = oacc[df][i] / lrow[i];
      wv[((size_t)b * Sq + qrow) * Em + h * Dh + d] = f2bf(o);
    }
  }
}

extern "C" void kernel_launch(void* const* d_in, const int* in_sizes, int n_in,
                              void* d_out, int out_size, void* d_ws, size_t ws_size,
                              hipStream_t stream) {
  (void)in_sizes; (void)n_in; (void)out_size; (void)ws_size;
  const float* query = (const float*)d_in[0];
  const float* key   = (const float*)d_in[1];
  const float* value = (const float*)d_in[2];
  const float* Wq = (const float*)d_in[3];
  const float* bq = (const float*)d_in[4];
  const float* Wk = (const float*)d_in[5];
  const float* bk = (const float*)d_in[6];
  const float* Wv = (const float*)d_in[7];
  const float* bv = (const float*)d_in[8];
  const float* Wo = (const float*)d_in[9];
  const float* bo = (const float*)d_in[10];
  const float* pos = (const float*)d_in[11];

  short* qx = (short*)d_ws;
  short* kx = qx + NE;
  short* vx = kx + NE;
  short* Wqb = vx + NE;
  short* Wkb = Wqb + WE;
  short* Wvb = Wkb + WE;
  short* Wob = Wvb + WE;
  short* qb = Wob + WE;
  short* wv = qx;                 // alias: qx dead after gemm_qkv
  short* kb = (short*)d_out;      // d_out scratch, overwritten by gemm_out
  short* vb = kb + NE;            // [B,H,Dh,S]

  convert_kernel<<<dim3(8192), 256, 0, stream>>>(
      query, key, value, Wq, Wk, Wv, Wo, qx, kx, vx, Wqb, Wkb, Wvb, Wob);
  gemm_qkv_bf16<<<dim3(Mrows / 128, Em / 128, 3), 256, 0, stream>>>(
      qx, kx, vx, Wqb, Wkb, Wvb, bq, bk, bv, pos, qb, kb, vb);
  attn_kernel<<<dim3(Bz * Hn, Sq / 64), 256, 0, stream>>>(qb, kb, vb, wv);
  gemm_out_bf16<<<dim3(Mrows / 128, Em / 128), 256, 0, stream>>>(
      wv, Wob, bo, (float*)d_out);
}

// Round 10
// 114.962 us; speedup vs baseline: 1.2543x; 1.0062x over previous
//
#include <hip/hip_runtime.h>
#include <hip/hip_bf16.h>

typedef __attribute__((ext_vector_type(8))) short bfx8;
typedef __attribute__((ext_vector_type(4))) short bfx4;
typedef __attribute__((ext_vector_type(4))) float fx4;

static __device__ __forceinline__ short f2bf(float f) {
  union { float f; unsigned u; } v; v.f = f;
  unsigned r = v.u + 0x7fffu + ((v.u >> 16) & 1u);
  return (short)(r >> 16);
}

static __device__ __forceinline__ void gld16(const void* g, void* l) {
  __builtin_amdgcn_global_load_lds(
      (const __attribute__((address_space(1))) void*)g,
      (__attribute__((address_space(3))) void*)l, 16, 0, 0);
}

constexpr int Bz = 8, Sq = 512, Em = 1024, Hn = 16, Dh = 64;
constexpr int Mrows = Bz * Sq;             // 4096
constexpr size_t NE = (size_t)Mrows * Em;  // 4,194,304
constexpr size_t WE = (size_t)Em * Em;     // 1,048,576

// ---------------- f32 -> bf16 pre-convert (memory-bound, exact flat grid) ----------------
__global__ __launch_bounds__(256) void convert_kernel(
    const float* __restrict__ q, const float* __restrict__ k,
    const float* __restrict__ v,
    const float* __restrict__ Wq, const float* __restrict__ Wk,
    const float* __restrict__ Wv, const float* __restrict__ Wo,
    short* __restrict__ qx, short* __restrict__ kx, short* __restrict__ vx,
    short* __restrict__ wqb, short* __restrict__ wkb,
    short* __restrict__ wvb, short* __restrict__ wob)
{
  const size_t c = (size_t)blockIdx.x * 256 + threadIdx.x;  // vec8 chunk id
  constexpr size_t CI = NE / 8;   // 524288
  constexpr size_t CW = WE / 8;   // 131072
  const float* src; short* dst; size_t off;
  if (c < 3 * CI) {
    const int sgi = (int)(c / CI);
    src = sgi == 0 ? q : sgi == 1 ? k : v;
    dst = sgi == 0 ? qx : sgi == 1 ? kx : vx;
    off = (c - (size_t)sgi * CI) * 8;
  } else {
    const size_t w = c - 3 * CI;
    const int sgi = (int)(w / CW);
    src = sgi == 0 ? Wq : sgi == 1 ? Wk : sgi == 2 ? Wv : Wo;
    dst = sgi == 0 ? wqb : sgi == 1 ? wkb : sgi == 2 ? wvb : wob;
    off = (w - (size_t)sgi * CW) * 8;
  }
  fx4 a = *(const fx4*)(src + off);
  fx4 b = *(const fx4*)(src + off + 4);
  bfx8 o = { f2bf(a[0]), f2bf(a[1]), f2bf(a[2]), f2bf(a[3]),
             f2bf(b[0]), f2bf(b[1]), f2bf(b[2]), f2bf(b[3]) };
  *(bfx8*)(dst + off) = o;
}

// ---------------- bf16 GEMM, C^T, BK=64 DOUBLE-buffered + counted vmcnt ----------------
// LDS 64KB: {A0,B0,A1,B1} each [128][64] bf16 (16KB). Per iter: issue next
// tile's 8 gld16 -> s_waitcnt vmcnt(8) (cur tile's 8 complete, FIFO) -> raw
// s_barrier -> compute cur -> raw barrier (WAR) -> swap. NO vmcnt(0) drain in
// the main loop (T3/T4; R6's failure was __syncthreads' implicit drain).
// XOR both-sides swizzle as R7. Epilogue C-tile reuses SM (union).
constexpr int LDP = 136;

__global__ __launch_bounds__(256, 4) void gemm_qkv_bf16(
    const short* __restrict__ qx, const short* __restrict__ kx,
    const short* __restrict__ vx,
    const short* __restrict__ Wqb, const short* __restrict__ Wkb,
    const short* __restrict__ Wvb,
    const float* __restrict__ bq, const float* __restrict__ bk,
    const float* __restrict__ bv,
    const float* __restrict__ pos,
    short* __restrict__ qb, short* __restrict__ kb, short* __restrict__ vb)
{
  __shared__ short SM[32768];          // 64KB
  short* A0 = SM;                      // [128][64]
  short* B0 = SM + 8192;
  short* A1 = SM + 16384;
  short* B1 = SM + 24576;

  const int z = blockIdx.z;
  const short* X = (z == 0) ? qx : (z == 1) ? kx : vx;
  const short* W = (z == 0) ? Wqb : (z == 1) ? Wkb : Wvb;
  const float* bias = (z == 0) ? bq : (z == 1) ? bk : bv;
  short* dst = (z == 0) ? qb : (z == 1) ? kb : vb;

  const int m0 = blockIdx.x * 128;
  const int n0 = blockIdx.y * 128;
  const int t = threadIdx.x, lane = t & 63, wave = t >> 6;
  const int wr = wave >> 1, wc = wave & 1;
  const int fr = lane & 15, fq = lane >> 4;

  const int trow = t >> 3;
  const int scol = ((t & 7) ^ (trow & 7)) * 8;
  const short* gW = W + (size_t)(n0 + trow) * Em + scol;
  const short* gX = X + (size_t)(m0 + trow) * Em + scol;
  const int lofs = wave * 512;

  const int sw0 = ((fq ^ (fr & 7)) * 8);
  const int sw1 = (((4 + fq) ^ (fr & 7)) * 8);

  fx4 acc[4][4] = {};

  auto stage = [&](int kk, short* Ab, short* Bb) {
#pragma unroll
    for (int r = 0; r < 4; ++r) {
      gld16(gW + (size_t)(32 * r) * Em + kk, Ab + lofs + r * 2048);
      gld16(gX + (size_t)(32 * r) * Em + kk, Bb + lofs + r * 2048);
    }
  };
  auto compute = [&](const short* As, const short* Bs) {
#pragma unroll
    for (int ks = 0; ks < 2; ++ks) {
      const int sw = ks ? sw1 : sw0;
      bfx8 af[4], bf[4];
#pragma unroll
      for (int u = 0; u < 4; ++u)
        af[u] = *(const bfx8*)&As[(wr * 64 + u * 16 + fr) * 64 + sw];
#pragma unroll
      for (int v = 0; v < 4; ++v)
        bf[v] = *(const bfx8*)&Bs[(wc * 64 + v * 16 + fr) * 64 + sw];
#pragma unroll
      for (int u = 0; u < 4; ++u)
#pragma unroll
        for (int v = 0; v < 4; ++v)
          acc[u][v] = __builtin_amdgcn_mfma_f32_16x16x32_bf16(af[u], bf[v], acc[u][v], 0, 0, 0);
    }
  };

  stage(0, A0, B0);                               // 8 outstanding
  for (int k0 = 0; k0 < Em; k0 += 128) {
    // half A: prefetch k0+64 -> buf1; wait cur 8 only; compute buf0
    stage(k0 + 64, A1, B1);
    __builtin_amdgcn_sched_barrier(0);
    asm volatile("s_waitcnt vmcnt(8)");
    __builtin_amdgcn_sched_barrier(0);
    __builtin_amdgcn_s_barrier();
    compute(A0, B0);
    __builtin_amdgcn_sched_barrier(0);
    __builtin_amdgcn_s_barrier();                 // WAR: all reads of buf0 done

    // half B: prefetch k0+128 -> buf0 (if any); compute buf1
    if (k0 + 128 < Em) {
      stage(k0 + 128, A0, B0);
      __builtin_amdgcn_sched_barrier(0);
      asm volatile("s_waitcnt vmcnt(8)");
    } else {
      asm volatile("s_waitcnt vmcnt(0)");
    }
    __builtin_amdgcn_sched_barrier(0);
    __builtin_amdgcn_s_barrier();
    compute(A1, B1);
    __builtin_amdgcn_sched_barrier(0);
    __builtin_amdgcn_s_barrier();                 // WAR: all reads of buf1 done
  }

  // ---- epilogue: +bias+pe, bounce through LDS, coalesced bfx8 stores ----
  const int rr = t >> 4, jj = t & 15;
  const int b = m0 >> 9;
  if (z < 2) {
#pragma unroll
    for (int u = 0; u < 4; ++u) {
      const int nn = wr * 64 + u * 16 + fq * 4;
      const int nng = n0 + nn;
      const fx4 bb = *(const fx4*)&bias[nng];
#pragma unroll
      for (int v = 0; v < 4; ++v) {
        const int m = wc * 64 + v * 16 + fr;
        const int s = (m0 + m) & (Sq - 1);
        const fx4 pe = *(const fx4*)&pos[(size_t)s * Em + nng];
        const fx4 a = acc[u][v];
        bfx4 o = { f2bf(a[0] + bb[0] + pe[0]), f2bf(a[1] + bb[1] + pe[1]),
                   f2bf(a[2] + bb[2] + pe[2]), f2bf(a[3] + bb[3] + pe[3]) };
        *(bfx4*)&SM[m * LDP + nn] = o;
      }
    }
    __syncthreads();
#pragma unroll
    for (int it = 0; it < 8; ++it) {
      const int m = it * 16 + rr;
      const int s = (m0 + m) & (Sq - 1);
      bfx8 val = *(const bfx8*)&SM[m * LDP + jj * 8];
      const int nng = n0 + jj * 8;
      const int h = nng >> 6, d = nng & 63;
      *(bfx8*)&dst[(((size_t)b * Hn + h) * Sq + s) * Dh + d] = val;
    }
  } else {
#pragma unroll
    for (int u = 0; u < 4; ++u) {
      const int nnb = wr * 64 + u * 16 + fq * 4;
      const int nng = n0 + nnb;
      const fx4 bb = *(const fx4*)&bias[nng];
#pragma unroll
      for (int v = 0; v < 4; ++v) {
        const int m = wc * 64 + v * 16 + fr;
        const int s = (m0 + m) & (Sq - 1);
        const fx4 pe = *(const fx4*)&pos[(size_t)s * Em + nng];
        const fx4 a = acc[u][v];
#pragma unroll
        for (int i = 0; i < 4; ++i) {
          const int row = nnb + i;
          SM[row * LDP + (m ^ ((row & 12) << 2))] = f2bf(a[i] + bb[i] + pe[i]);
        }
      }
    }
    __syncthreads();
    const int s0 = m0 & (Sq - 1);
#pragma unroll
    for (int it = 0; it < 8; ++it) {
      const int row = it * 16 + rr;
      bfx8 val = *(const bfx8*)&SM[row * LDP + ((jj * 8) ^ ((row & 12) << 2))];
      const int nng = n0 + row;
      const int h = nng >> 6, d = nng & 63;
      *(bfx8*)&dst[(((size_t)b * Hn + h) * Dh + d) * Sq + s0 + jj * 8] = val;
    }
  }
}

// output projection: out = wv @ Wo^T + bo  (same dbuf+counted-vmcnt loop)
__global__ __launch_bounds__(256, 4) void gemm_out_bf16(
    const short* __restrict__ wv, const short* __restrict__ Wob,
    const float* __restrict__ bo, float* __restrict__ out)
{
  __shared__ short SM[32768];
  short* A0 = SM;
  short* B0 = SM + 8192;
  short* A1 = SM + 16384;
  short* B1 = SM + 24576;

  const int m0 = blockIdx.x * 128;
  const int n0 = blockIdx.y * 128;
  const int t = threadIdx.x, lane = t & 63, wave = t >> 6;
  const int wr = wave >> 1, wc = wave & 1;
  const int fr = lane & 15, fq = lane >> 4;

  const int trow = t >> 3;
  const int scol = ((t & 7) ^ (trow & 7)) * 8;
  const short* gW = Wob + (size_t)(n0 + trow) * Em + scol;
  const short* gX = wv + (size_t)(m0 + trow) * Em + scol;
  const int lofs = wave * 512;

  const int sw0 = ((fq ^ (fr & 7)) * 8);
  const int sw1 = (((4 + fq) ^ (fr & 7)) * 8);

  fx4 acc[4][4] = {};

  auto stage = [&](int kk, short* Ab, short* Bb) {
#pragma unroll
    for (int r = 0; r < 4; ++r) {
      gld16(gW + (size_t)(32 * r) * Em + kk, Ab + lofs + r * 2048);
      gld16(gX + (size_t)(32 * r) * Em + kk, Bb + lofs + r * 2048);
    }
  };
  auto compute = [&](const short* As, const short* Bs) {
#pragma unroll
    for (int ks = 0; ks < 2; ++ks) {
      const int sw = ks ? sw1 : sw0;
      bfx8 af[4], bf[4];
#pragma unroll
      for (int u = 0; u < 4; ++u)
        af[u] = *(const bfx8*)&As[(wr * 64 + u * 16 + fr) * 64 + sw];
#pragma unroll
      for (int v = 0; v < 4; ++v)
        bf[v] = *(const bfx8*)&Bs[(wc * 64 + v * 16 + fr) * 64 + sw];
#pragma unroll
      for (int u = 0; u < 4; ++u)
#pragma unroll
        for (int v = 0; v < 4; ++v)
          acc[u][v] = __builtin_amdgcn_mfma_f32_16x16x32_bf16(af[u], bf[v], acc[u][v], 0, 0, 0);
    }
  };

  stage(0, A0, B0);
  for (int k0 = 0; k0 < Em; k0 += 128) {
    stage(k0 + 64, A1, B1);
    __builtin_amdgcn_sched_barrier(0);
    asm volatile("s_waitcnt vmcnt(8)");
    __builtin_amdgcn_sched_barrier(0);
    __builtin_amdgcn_s_barrier();
    compute(A0, B0);
    __builtin_amdgcn_sched_barrier(0);
    __builtin_amdgcn_s_barrier();

    if (k0 + 128 < Em) {
      stage(k0 + 128, A0, B0);
      __builtin_amdgcn_sched_barrier(0);
      asm volatile("s_waitcnt vmcnt(8)");
    } else {
      asm volatile("s_waitcnt vmcnt(0)");
    }
    __builtin_amdgcn_sched_barrier(0);
    __builtin_amdgcn_s_barrier();
    compute(A1, B1);
    __builtin_amdgcn_sched_barrier(0);
    __builtin_amdgcn_s_barrier();
  }

#pragma unroll
  for (int u = 0; u < 4; ++u) {
    const int nn = n0 + wr * 64 + u * 16 + fq * 4;
    const fx4 bb = *(const fx4*)&bo[nn];
#pragma unroll
    for (int v = 0; v < 4; ++v) {
      const int m = m0 + wc * 64 + v * 16 + fr;
      fx4 val = acc[u][v];
      val[0] += bb[0]; val[1] += bb[1]; val[2] += bb[2]; val[3] += bb[3];
      *(fx4*)&out[(size_t)m * Em + nn] = val;
    }
  }
}

// ---------------- Attention: LDS-staged + T14 async-STAGE split (R9, unchanged) ----------------
constexpr int KVB = 64, LDK = 72;

__global__ __launch_bounds__(256) void attn_kernel(
    const short* __restrict__ qb, const short* __restrict__ kb,
    const short* __restrict__ vb, short* __restrict__ wv)
{
  __shared__ short Ks[KVB * LDK];
  __shared__ short Vt[Dh * LDK];
  __shared__ short Ps[4][16 * LDK];

  const int bh = blockIdx.x;
  const int qt = blockIdx.y;
  const int t = threadIdx.x, lane = t & 63, wave = t >> 6;
  const int fr = lane & 15, fq = lane >> 4;

  const size_t base = (size_t)bh * Sq * Dh;
  const int q0 = qt * 64 + wave * 16;

  bfx8 qf[2];
  {
    const short* qp = qb + base + (size_t)(q0 + fr) * Dh;
    qf[0] = *(const bfx8*)(qp + fq * 8);
    qf[1] = *(const bfx8*)(qp + 32 + fq * 8);
  }

  const int kr = t >> 2, kc = (t & 3) * 16;
  const short* kbp = kb + base + (size_t)kr * Dh + kc;
  const short* vbp = vb + base + (size_t)kr * Sq + kc;

  {
    bfx8 k0 = *(const bfx8*)kbp;
    bfx8 k1 = *(const bfx8*)(kbp + 8);
    bfx8 v0 = *(const bfx8*)vbp;
    bfx8 v1 = *(const bfx8*)(vbp + 8);
    *(bfx8*)&Ks[kr * LDK + kc] = k0;
    *(bfx8*)&Ks[kr * LDK + kc + 8] = k1;
    *(bfx8*)&Vt[kr * LDK + kc] = v0;
    *(bfx8*)&Vt[kr * LDK + kc + 8] = v1;
  }
  __syncthreads();

  float mrow[4] = { -1e30f, -1e30f, -1e30f, -1e30f };
  float lrow[4] = { 0.f, 0.f, 0.f, 0.f };
  fx4 oacc[4] = {};

  for (int kv0 = 0; kv0 < Sq; kv0 += KVB) {
    const bool more = (kv0 + KVB) < Sq;
    bfx8 nk0, nk1, nv0, nv1;
    if (more) {
      const short* nk = kbp + (size_t)(kv0 + KVB) * Dh;
      const short* nv = vbp + (kv0 + KVB);
      nk0 = *(const bfx8*)nk;
      nk1 = *(const bfx8*)(nk + 8);
      nv0 = *(const bfx8*)nv;
      nv1 = *(const bfx8*)(nv + 8);
    }

    fx4 sa[4] = {};
#pragma unroll
    for (int nf = 0; nf < 4; ++nf) {
#pragma unroll
      for (int ks = 0; ks < 2; ++ks) {
        bfx8 kf = *(const bfx8*)&Ks[(nf * 16 + fr) * LDK + ks * 32 + fq * 8];
        sa[nf] = __builtin_amdgcn_mfma_f32_16x16x32_bf16(qf[ks], kf, sa[nf], 0, 0, 0);
      }
    }

#pragma unroll
    for (int i = 0; i < 4; ++i) {
      float mx = fmaxf(fmaxf(sa[0][i], sa[1][i]), fmaxf(sa[2][i], sa[3][i]));
      mx = fmaxf(mx, __shfl_xor(mx, 1));
      mx = fmaxf(mx, __shfl_xor(mx, 2));
      mx = fmaxf(mx, __shfl_xor(mx, 4));
      mx = fmaxf(mx, __shfl_xor(mx, 8));
      mx *= 0.125f;
      const float mn = fmaxf(mrow[i], mx);
      const float alpha = __expf(mrow[i] - mn);
      mrow[i] = mn;
      float rs = 0.f;
#pragma unroll
      for (int nf = 0; nf < 4; ++nf) {
        const float p = __expf(sa[nf][i] * 0.125f - mn);
        rs += p;
        Ps[wave][(fq * 4 + i) * LDK + nf * 16 + fr] = f2bf(p);
      }
      rs += __shfl_xor(rs, 1);
      rs += __shfl_xor(rs, 2);
      rs += __shfl_xor(rs, 4);
      rs += __shfl_xor(rs, 8);
      lrow[i] = lrow[i] * alpha + rs;
#pragma unroll
      for (int df = 0; df < 4; ++df) oacc[df][i] *= alpha;
    }

    bfx8 pf[2];
    pf[0] = *(const bfx8*)&Ps[wave][fr * LDK + fq * 8];
    pf[1] = *(const bfx8*)&Ps[wave][fr * LDK + 32 + fq * 8];
#pragma unroll
    for (int df = 0; df < 4; ++df) {
#pragma unroll
      for (int ks = 0; ks < 2; ++ks) {
        bfx8 vf = *(const bfx8*)&Vt[(df * 16 + fr) * LDK + ks * 32 + fq * 8];
        oacc[df] = __builtin_amdgcn_mfma_f32_16x16x32_bf16(pf[ks], vf, oacc[df], 0, 0, 0);
      }
    }
    __syncthreads();

    if (more) {
      *(bfx8*)&Ks[kr * LDK + kc] = nk0;
      *(bfx8*)&Ks[kr * LDK + kc + 8] = nk1;
      *(bfx8*)&Vt[kr * LDK + kc] = nv0;
      *(bfx8*)&Vt[kr * LDK + kc + 8] = nv1;
      __syncthreads();
    }
  }

  const int b = bh >> 4, h = bh & 15;
#pragma unroll
  for (int df = 0; df < 4; ++df) {
    const int d = df * 16 + fr;
#pragma unroll
    for (int i = 0; i < 4; ++i) {
      const int qrow = q0 + fq * 4 + i;
      const float o = oacc[df][i] / lrow[i];
      wv[((size_t)b * Sq + qrow) * Em + h * Dh + d] = f2bf(o);
    }
  }
}

extern "C" void kernel_launch(void* const* d_in, const int* in_sizes, int n_in,
                              void* d_out, int out_size, void* d_ws, size_t ws_size,
                              hipStream_t stream) {
  (void)in_sizes; (void)n_in; (void)out_size; (void)ws_size;
  const float* query = (const float*)d_in[0];
  const float* key   = (const float*)d_in[1];
  const float* value = (const float*)d_in[2];
  const float* Wq = (const float*)d_in[3];
  const float* bq = (const float*)d_in[4];
  const float* Wk = (const float*)d_in[5];
  const float* bk = (const float*)d_in[6];
  const float* Wv = (const float*)d_in[7];
  const float* bv = (const float*)d_in[8];
  const float* Wo = (const float*)d_in[9];
  const float* bo = (const float*)d_in[10];
  const float* pos = (const float*)d_in[11];

  short* qx = (short*)d_ws;
  short* kx = qx + NE;
  short* vx = kx + NE;
  short* Wqb = vx + NE;
  short* Wkb = Wqb + WE;
  short* Wvb = Wkb + WE;
  short* Wob = Wvb + WE;
  short* qb = Wob + WE;
  short* wv = qx;                 // alias: qx dead after gemm_qkv
  short* kb = (short*)d_out;      // d_out scratch, overwritten by gemm_out
  short* vb = kb + NE;            // [B,H,Dh,S]

  convert_kernel<<<dim3(8192), 256, 0, stream>>>(
      query, key, value, Wq, Wk, Wv, Wo, qx, kx, vx, Wqb, Wkb, Wvb, Wob);
  gemm_qkv_bf16<<<dim3(Mrows / 128, Em / 128, 3), 256, 0, stream>>>(
      qx, kx, vx, Wqb, Wkb, Wvb, bq, bk, bv, pos, qb, kb, vb);
  attn_kernel<<<dim3(Bz * Hn, Sq / 64), 256, 0, stream>>>(qb, kb, vb, wv);
  gemm_out_bf16<<<dim3(Mrows / 128, Em / 128), 256, 0, stream>>>(
      wv, Wob, bo, (float*)d_out);
}

// Round 11
// 111.040 us; speedup vs baseline: 1.2986x; 1.0353x over previous
//
#include <hip/hip_runtime.h>
#include <hip/hip_bf16.h>

typedef __attribute__((ext_vector_type(8))) short bfx8;
typedef __attribute__((ext_vector_type(4))) short bfx4;
typedef __attribute__((ext_vector_type(4))) float fx4;

static __device__ __forceinline__ short f2bf(float f) {
  union { float f; unsigned u; } v; v.f = f;
  unsigned r = v.u + 0x7fffu + ((v.u >> 16) & 1u);
  return (short)(r >> 16);
}

static __device__ __forceinline__ void gld16(const void* g, void* l) {
  __builtin_amdgcn_global_load_lds(
      (const __attribute__((address_space(1))) void*)g,
      (__attribute__((address_space(3))) void*)l, 16, 0, 0);
}

constexpr int Bz = 8, Sq = 512, Em = 1024, Hn = 16, Dh = 64;
constexpr int Mrows = Bz * Sq;             // 4096
constexpr size_t NE = (size_t)Mrows * Em;  // 4,194,304
constexpr size_t WE = (size_t)Em * Em;     // 1,048,576
constexpr int NT = Em / 64;                // 16 K-tiles

// ---------------- f32 -> bf16 pre-convert (R9, unchanged) ----------------
__global__ __launch_bounds__(256) void convert_kernel(
    const float* __restrict__ q, const float* __restrict__ k,
    const float* __restrict__ v,
    const float* __restrict__ Wq, const float* __restrict__ Wk,
    const float* __restrict__ Wv, const float* __restrict__ Wo,
    short* __restrict__ qx, short* __restrict__ kx, short* __restrict__ vx,
    short* __restrict__ wqb, short* __restrict__ wkb,
    short* __restrict__ wvb, short* __restrict__ wob)
{
  const size_t c = (size_t)blockIdx.x * 256 + threadIdx.x;
  constexpr size_t CI = NE / 8;
  constexpr size_t CW = WE / 8;
  const float* src; short* dst; size_t off;
  if (c < 3 * CI) {
    const int sgi = (int)(c / CI);
    src = sgi == 0 ? q : sgi == 1 ? k : v;
    dst = sgi == 0 ? qx : sgi == 1 ? kx : vx;
    off = (c - (size_t)sgi * CI) * 8;
  } else {
    const size_t w = c - 3 * CI;
    const int sgi = (int)(w / CW);
    src = sgi == 0 ? Wq : sgi == 1 ? Wk : sgi == 2 ? Wv : Wo;
    dst = sgi == 0 ? wqb : sgi == 1 ? wkb : sgi == 2 ? wvb : wob;
    off = (w - (size_t)sgi * CW) * 8;
  }
  fx4 a = *(const fx4*)(src + off);
  fx4 b = *(const fx4*)(src + off + 4);
  bfx8 o = { f2bf(a[0]), f2bf(a[1]), f2bf(a[2]), f2bf(a[3]),
             f2bf(b[0]), f2bf(b[1]), f2bf(b[2]), f2bf(b[3]) };
  *(bfx8*)(dst + off) = o;
}

// ---------------- gemm_qkv: 256x256 tile, 8 waves, 4-phase/K-tile schedule ----------------
// C^T orientation: A=W (features, 256), B=X (tokens, 256). Per-wave 128x64.
// LDS 128KB: slot p in {0,1}: A[2 halves][128][64] + B[2 halves][128][64].
// Per K-tile (4 phases): ph0 {B-frags 8 + A-rows0,1 ds_read; stage A-halves of kt+1},
// ph1 {A-rows2,3; stage B-halves}, ph2 {A-rows4,5}, ph3 {A-rows6,7; vmcnt(0) post-MFMA}.
// Each phase: reads/stage -> s_barrier -> setprio(1) -> 16 MFMA -> setprio(0) -> s_barrier.
// XOR swizzle both-sides (R7): LDS linear dest, source col (c&7)^(row&7), read (kh*4+fq)^(fr&7).
__global__ __launch_bounds__(512, 2) void gemm_qkv_bf16(
    const short* __restrict__ qx, const short* __restrict__ kx,
    const short* __restrict__ vx,
    const short* __restrict__ Wqb, const short* __restrict__ Wkb,
    const short* __restrict__ Wvb,
    const float* __restrict__ bq, const float* __restrict__ bk,
    const float* __restrict__ bv,
    const float* __restrict__ pos,
    short* __restrict__ qb, short* __restrict__ kb, short* __restrict__ vb)
{
  __shared__ short SM[65536];   // 128KB

  const int z = blockIdx.z;
  const short* X = (z == 0) ? qx : (z == 1) ? kx : vx;
  const short* W = (z == 0) ? Wqb : (z == 1) ? Wkb : Wvb;
  const float* bias = (z == 0) ? bq : (z == 1) ? bk : bv;
  short* dst = (z == 0) ? qb : (z == 1) ? kb : vb;

  const int t0b = blockIdx.x * 256;   // token base (fast axis -> XCD locality)
  const int f0 = blockIdx.y * 256;    // feature base
  const int t = threadIdx.x, lane = t & 63, wave = t >> 6;
  const int wr = wave >> 2;           // feature half (0,1)
  const int wn = wave & 3;            // token quarter (0..3)
  const int fr = lane & 15, fq = lane >> 4;

  // staging constants (per half-tile: 2 gld16/thread)
  const int srow = t >> 3;                  // 0..63
  const int scc = (t & 7) ^ (srow & 7);     // swizzled source col chunk
  const int sdst = wave * 512;              // LDS dest base (elems), +4096 for l=1

  const int sw0 = (fq ^ (fr & 7)) * 8;
  const int sw1 = ((4 + fq) ^ (fr & 7)) * 8;

  auto stageA = [&](int hh, int ktn, int pn) {
    const short* s = W + (size_t)(f0 + hh * 128 + srow) * Em + ktn * 64 + scc * 8;
    short* d = SM + pn * 32768 + hh * 8192 + sdst;
    gld16(s, d);
    gld16(s + (size_t)64 * Em, d + 4096);
  };
  auto stageB = [&](int hh, int ktn, int pn) {
    const short* s = X + (size_t)(t0b + hh * 128 + srow) * Em + ktn * 64 + scc * 8;
    short* d = SM + pn * 32768 + 16384 + hh * 8192 + sdst;
    gld16(s, d);
    gld16(s + (size_t)64 * Em, d + 4096);
  };

  fx4 acc[8][4] = {};

  // prologue: stage K-tile 0 (4 halves, 8 gld/thread), drain, barrier
  stageA(0, 0, 0); stageA(1, 0, 0); stageB(0, 0, 0); stageB(1, 0, 0);
  __builtin_amdgcn_sched_barrier(0);
  asm volatile("s_waitcnt vmcnt(0)");
  __builtin_amdgcn_sched_barrier(0);
  __builtin_amdgcn_s_barrier();

  for (int kt = 0; kt < NT; ++kt) {
    const int p = kt & 1, pn = p ^ 1;
    const int ktn = (kt + 1 < NT) ? kt + 1 : 0;   // wrap keeps gld counts uniform
    const short* Ab = SM + p * 32768 + wr * 8192;
    const short* Bb = SM + p * 32768 + 16384 + (wn >> 1) * 8192 + (wn & 1) * 4096;

    bfx8 bf[4][2];
#pragma unroll
    for (int q = 0; q < 4; ++q) {
      // ---- read phase ----
      if (q == 0) {
#pragma unroll
        for (int cg = 0; cg < 4; ++cg) {
          bf[cg][0] = *(const bfx8*)&Bb[(cg * 16 + fr) * 64 + sw0];
          bf[cg][1] = *(const bfx8*)&Bb[(cg * 16 + fr) * 64 + sw1];
        }
      }
      bfx8 af[2][2];
#pragma unroll
      for (int rr2 = 0; rr2 < 2; ++rr2) {
        const int row = (q * 2 + rr2) * 16 + fr;
        af[rr2][0] = *(const bfx8*)&Ab[row * 64 + sw0];
        af[rr2][1] = *(const bfx8*)&Ab[row * 64 + sw1];
      }
      // ---- stage phase (1st half of K-tile's staging in ph0, 2nd in ph1) ----
      if (q == 0) { stageA(0, ktn, pn); stageA(1, ktn, pn); }
      if (q == 1) { stageB(0, ktn, pn); stageB(1, ktn, pn); }

      __builtin_amdgcn_sched_barrier(0);
      __builtin_amdgcn_s_barrier();
      __builtin_amdgcn_sched_barrier(0);

      // ---- MFMA cluster (16) ----
      __builtin_amdgcn_s_setprio(1);
#pragma unroll
      for (int rr2 = 0; rr2 < 2; ++rr2)
#pragma unroll
        for (int cg = 0; cg < 4; ++cg) {
          acc[q * 2 + rr2][cg] = __builtin_amdgcn_mfma_f32_16x16x32_bf16(
              af[rr2][0], bf[cg][0], acc[q * 2 + rr2][cg], 0, 0, 0);
          acc[q * 2 + rr2][cg] = __builtin_amdgcn_mfma_f32_16x16x32_bf16(
              af[rr2][1], bf[cg][1], acc[q * 2 + rr2][cg], 0, 0, 0);
        }
      __builtin_amdgcn_s_setprio(0);
      __builtin_amdgcn_sched_barrier(0);

      if (q == 3) {  // confirm next K-tile's staging landed (issued >=2 phases ago)
        asm volatile("s_waitcnt vmcnt(0)");
        __builtin_amdgcn_sched_barrier(0);
      }
      __builtin_amdgcn_s_barrier();
    }
  }

  // ---- epilogue: 2 passes over feature halves, LDS bounce, coalesced stores ----
  const int b = t0b >> 9;
  if (z < 2) {
#pragma unroll
    for (int fp = 0; fp < 2; ++fp) {
      if (fp) __syncthreads();
      if (wr == fp) {
#pragma unroll
        for (int rg = 0; rg < 8; ++rg) {
          const int nloc = rg * 16 + fq * 4;
          const int nng = f0 + fp * 128 + nloc;
          const fx4 bb = *(const fx4*)&bias[nng];
#pragma unroll
          for (int cg = 0; cg < 4; ++cg) {
            const int token = wn * 64 + cg * 16 + fr;
            const int s = (t0b + token) & (Sq - 1);
            const fx4 pe = *(const fx4*)&pos[(size_t)s * Em + nng];
            const fx4 a = acc[rg][cg];
            bfx4 o = { f2bf(a[0] + bb[0] + pe[0]), f2bf(a[1] + bb[1] + pe[1]),
                       f2bf(a[2] + bb[2] + pe[2]), f2bf(a[3] + bb[3] + pe[3]) };
            *(bfx4*)&SM[token * 136 + nloc] = o;
          }
        }
      }
      __syncthreads();
#pragma unroll
      for (int it = 0; it < 8; ++it) {
        const int flat = it * 512 + t;
        const int token = flat >> 4, ch = flat & 15;
        bfx8 val = *(const bfx8*)&SM[token * 136 + ch * 8];
        const int nng = f0 + fp * 128 + ch * 8;
        const int h = nng >> 6, d = nng & 63;
        const int s = (t0b + token) & (Sq - 1);
        *(bfx8*)&dst[(((size_t)b * Hn + h) * Sq + s) * Dh + d] = val;
      }
    }
  } else {
    // V transposed [B,H,Dh,S]: bounce [feature][token]
#pragma unroll
    for (int fp = 0; fp < 2; ++fp) {
      if (fp) __syncthreads();
      if (wr == fp) {
#pragma unroll
        for (int rg = 0; rg < 8; ++rg) {
          const int nloc = rg * 16 + fq * 4;
          const int nng = f0 + fp * 128 + nloc;
          const fx4 bb = *(const fx4*)&bias[nng];
#pragma unroll
          for (int cg = 0; cg < 4; ++cg) {
            const int token = wn * 64 + cg * 16 + fr;
            const int s = (t0b + token) & (Sq - 1);
            const fx4 pe = *(const fx4*)&pos[(size_t)s * Em + nng];
            const fx4 a = acc[rg][cg];
#pragma unroll
            for (int i = 0; i < 4; ++i)
              SM[(nloc + i) * 264 + token] = f2bf(a[i] + bb[i] + pe[i]);
          }
        }
      }
      __syncthreads();
      const int s0 = t0b & (Sq - 1);
#pragma unroll
      for (int it = 0; it < 8; ++it) {
        const int flat = it * 512 + t;
        const int row = flat >> 5, ch = flat & 31;
        bfx8 val = *(const bfx8*)&SM[row * 264 + ch * 8];
        const int nng = f0 + fp * 128 + row;
        const int h = nng >> 6, d = nng & 63;
        *(bfx8*)&dst[(((size_t)b * Hn + h) * Dh + d) * Sq + s0 + ch * 8] = val;
      }
    }
  }
}

// ---------------- gemm_out (R9/R7 proven version, unchanged) ----------------
constexpr int LDP = 136;

__global__ __launch_bounds__(256, 4) void gemm_out_bf16(
    const short* __restrict__ wv, const short* __restrict__ Wob,
    const float* __restrict__ bo, float* __restrict__ out)
{
  __shared__ short SMo[2 * 8192];
  short* As = SMo;
  short* Bs = SMo + 8192;

  const int m0 = blockIdx.x * 128;
  const int n0 = blockIdx.y * 128;
  const int t = threadIdx.x, lane = t & 63, wave = t >> 6;
  const int wr = wave >> 1, wc = wave & 1;
  const int fr = lane & 15, fq = lane >> 4;

  const int trow = t >> 3;
  const int scol = ((t & 7) ^ (trow & 7)) * 8;
  const short* gW = Wob + (size_t)(n0 + trow) * Em + scol;
  const short* gX = wv + (size_t)(m0 + trow) * Em + scol;
  short* lA = As + wave * 512;
  short* lB = Bs + wave * 512;

  const int sw0 = ((fq ^ (fr & 7)) * 8);
  const int sw1 = (((4 + fq) ^ (fr & 7)) * 8);

  fx4 acc[4][4] = {};

  for (int k0 = 0; k0 < Em; k0 += 64) {
#pragma unroll
    for (int r = 0; r < 4; ++r) {
      gld16(gW + (size_t)(32 * r) * Em + k0, lA + r * 2048);
      gld16(gX + (size_t)(32 * r) * Em + k0, lB + r * 2048);
    }
    __syncthreads();

#pragma unroll
    for (int ks = 0; ks < 2; ++ks) {
      const int sw = ks ? sw1 : sw0;
      bfx8 af[4], bf[4];
#pragma unroll
      for (int u = 0; u < 4; ++u)
        af[u] = *(const bfx8*)&As[(wr * 64 + u * 16 + fr) * 64 + sw];
#pragma unroll
      for (int v = 0; v < 4; ++v)
        bf[v] = *(const bfx8*)&Bs[(wc * 64 + v * 16 + fr) * 64 + sw];
#pragma unroll
      for (int u = 0; u < 4; ++u)
#pragma unroll
        for (int v = 0; v < 4; ++v)
          acc[u][v] = __builtin_amdgcn_mfma_f32_16x16x32_bf16(af[u], bf[v], acc[u][v], 0, 0, 0);
    }
    __syncthreads();
  }

#pragma unroll
  for (int u = 0; u < 4; ++u) {
    const int nn = n0 + wr * 64 + u * 16 + fq * 4;
    const fx4 bb = *(const fx4*)&bo[nn];
#pragma unroll
    for (int v = 0; v < 4; ++v) {
      const int m = m0 + wc * 64 + v * 16 + fr;
      fx4 val = acc[u][v];
      val[0] += bb[0]; val[1] += bb[1]; val[2] += bb[2]; val[3] += bb[3];
      *(fx4*)&out[(size_t)m * Em + nn] = val;
    }
  }
}

// ---------------- Attention (R9, unchanged) ----------------
constexpr int KVB = 64, LDK = 72;

__global__ __launch_bounds__(256) void attn_kernel(
    const short* __restrict__ qb, const short* __restrict__ kb,
    const short* __restrict__ vb, short* __restrict__ wv)
{
  __shared__ short Ks[KVB * LDK];
  __shared__ short Vt[Dh * LDK];
  __shared__ short Ps[4][16 * LDK];

  const int bh = blockIdx.x;
  const int qt = blockIdx.y;
  const int t = threadIdx.x, lane = t & 63, wave = t >> 6;
  const int fr = lane & 15, fq = lane >> 4;

  const size_t base = (size_t)bh * Sq * Dh;
  const int q0 = qt * 64 + wave * 16;

  bfx8 qf[2];
  {
    const short* qp = qb + base + (size_t)(q0 + fr) * Dh;
    qf[0] = *(const bfx8*)(qp + fq * 8);
    qf[1] = *(const bfx8*)(qp + 32 + fq * 8);
  }

  const int kr = t >> 2, kc = (t & 3) * 16;
  const short* kbp = kb + base + (size_t)kr * Dh + kc;
  const short* vbp = vb + base + (size_t)kr * Sq + kc;

  {
    bfx8 k0 = *(const bfx8*)kbp;
    bfx8 k1 = *(const bfx8*)(kbp + 8);
    bfx8 v0 = *(const bfx8*)vbp;
    bfx8 v1 = *(const bfx8*)(vbp + 8);
    *(bfx8*)&Ks[kr * LDK + kc] = k0;
    *(bfx8*)&Ks[kr * LDK + kc + 8] = k1;
    *(bfx8*)&Vt[kr * LDK + kc] = v0;
    *(bfx8*)&Vt[kr * LDK + kc + 8] = v1;
  }
  __syncthreads();

  float mrow[4] = { -1e30f, -1e30f, -1e30f, -1e30f };
  float lrow[4] = { 0.f, 0.f, 0.f, 0.f };
  fx4 oacc[4] = {};

  for (int kv0 = 0; kv0 < Sq; kv0 += KVB) {
    const bool more = (kv0 + KVB) < Sq;
    bfx8 nk0, nk1, nv0, nv1;
    if (more) {
      const short* nk = kbp + (size_t)(kv0 + KVB) * Dh;
      const short* nv = vbp + (kv0 + KVB);
      nk0 = *(const bfx8*)nk;
      nk1 = *(const bfx8*)(nk + 8);
      nv0 = *(const bfx8*)nv;
      nv1 = *(const bfx8*)(nv + 8);
    }

    fx4 sa[4] = {};
#pragma unroll
    for (int nf = 0; nf < 4; ++nf) {
#pragma unroll
      for (int ks = 0; ks < 2; ++ks) {
        bfx8 kf = *(const bfx8*)&Ks[(nf * 16 + fr) * LDK + ks * 32 + fq * 8];
        sa[nf] = __builtin_amdgcn_mfma_f32_16x16x32_bf16(qf[ks], kf, sa[nf], 0, 0, 0);
      }
    }

#pragma unroll
    for (int i = 0; i < 4; ++i) {
      float mx = fmaxf(fmaxf(sa[0][i], sa[1][i]), fmaxf(sa[2][i], sa[3][i]));
      mx = fmaxf(mx, __shfl_xor(mx, 1));
      mx = fmaxf(mx, __shfl_xor(mx, 2));
      mx = fmaxf(mx, __shfl_xor(mx, 4));
      mx = fmaxf(mx, __shfl_xor(mx, 8));
      mx *= 0.125f;
      const float mn = fmaxf(mrow[i], mx);
      const float alpha = __expf(mrow[i] - mn);
      mrow[i] = mn;
      float rs = 0.f;
#pragma unroll
      for (int nf = 0; nf < 4; ++nf) {
        const float p = __expf(sa[nf][i] * 0.125f - mn);
        rs += p;
        Ps[wave][(fq * 4 + i) * LDK + nf * 16 + fr] = f2bf(p);
      }
      rs += __shfl_xor(rs, 1);
      rs += __shfl_xor(rs, 2);
      rs += __shfl_xor(rs, 4);
      rs += __shfl_xor(rs, 8);
      lrow[i] = lrow[i] * alpha + rs;
#pragma unroll
      for (int df = 0; df < 4; ++df) oacc[df][i] *= alpha;
    }

    bfx8 pf[2];
    pf[0] = *(const bfx8*)&Ps[wave][fr * LDK + fq * 8];
    pf[1] = *(const bfx8*)&Ps[wave][fr * LDK + 32 + fq * 8];
#pragma unroll
    for (int df = 0; df < 4; ++df) {
#pragma unroll
      for (int ks = 0; ks < 2; ++ks) {
        bfx8 vf = *(const bfx8*)&Vt[(df * 16 + fr) * LDK + ks * 32 + fq * 8];
        oacc[df] = __builtin_amdgcn_mfma_f32_16x16x32_bf16(pf[ks], vf, oacc[df], 0, 0, 0);
      }
    }
    __syncthreads();

    if (more) {
      *(bfx8*)&Ks[kr * LDK + kc] = nk0;
      *(bfx8*)&Ks[kr * LDK + kc + 8] = nk1;
      *(bfx8*)&Vt[kr * LDK + kc] = nv0;
      *(bfx8*)&Vt[kr * LDK + kc + 8] = nv1;
      __syncthreads();
    }
  }

  const int b = bh >> 4, h = bh & 15;
#pragma unroll
  for (int df = 0; df < 4; ++df) {
    const int d = df * 16 + fr;
#pragma unroll
    for (int i = 0; i < 4; ++i) {
      const int qrow = q0 + fq * 4 + i;
      const float o = oacc[df][i] / lrow[i];
      wv[((size_t)b * Sq + qrow) * Em + h * Dh + d] = f2bf(o);
    }
  }
}

extern "C" void kernel_launch(void* const* d_in, const int* in_sizes, int n_in,
                              void* d_out, int out_size, void* d_ws, size_t ws_size,
                              hipStream_t stream) {
  (void)in_sizes; (void)n_in; (void)out_size; (void)ws_size;
  const float* query = (const float*)d_in[0];
  const float* key   = (const float*)d_in[1];
  const float* value = (const float*)d_in[2];
  const float* Wq = (const float*)d_in[3];
  const float* bq = (const float*)d_in[4];
  const float* Wk = (const float*)d_in[5];
  const float* bk = (const float*)d_in[6];
  const float* Wv = (const float*)d_in[7];
  const float* bv = (const float*)d_in[8];
  const float* Wo = (const float*)d_in[9];
  const float* bo = (const float*)d_in[10];
  const float* pos = (const float*)d_in[11];

  short* qx = (short*)d_ws;
  short* kx = qx + NE;
  short* vx = kx + NE;
  short* Wqb = vx + NE;
  short* Wkb = Wqb + WE;
  short* Wvb = Wkb + WE;
  short* Wob = Wvb + WE;
  short* qb = Wob + WE;
  short* wv = qx;                 // alias: qx dead after gemm_qkv
  short* kb = (short*)d_out;      // d_out scratch, overwritten by gemm_out
  short* vb = kb + NE;            // [B,H,Dh,S]

  convert_kernel<<<dim3(8192), 256, 0, stream>>>(
      query, key, value, Wq, Wk, Wv, Wo, qx, kx, vx, Wqb, Wkb, Wvb, Wob);
  gemm_qkv_bf16<<<dim3(Mrows / 256, Em / 256, 3), 512, 0, stream>>>(
      qx, kx, vx, Wqb, Wkb, Wvb, bq, bk, bv, pos, qb, kb, vb);
  attn_kernel<<<dim3(Bz * Hn, Sq / 64), 256, 0, stream>>>(qb, kb, vb, wv);
  gemm_out_bf16<<<dim3(Mrows / 128, Em / 128), 256, 0, stream>>>(
      wv, Wob, bo, (float*)d_out);
}

// Round 12
// 109.696 us; speedup vs baseline: 1.3145x; 1.0122x over previous
//
#include <hip/hip_runtime.h>
#include <hip/hip_bf16.h>

typedef __attribute__((ext_vector_type(8))) short bfx8;
typedef __attribute__((ext_vector_type(4))) short bfx4;
typedef __attribute__((ext_vector_type(4))) float fx4;

static __device__ __forceinline__ short f2bf(float f) {
  union { float f; unsigned u; } v; v.f = f;
  unsigned r = v.u + 0x7fffu + ((v.u >> 16) & 1u);
  return (short)(r >> 16);
}

static __device__ __forceinline__ void gld16(const void* g, void* l) {
  __builtin_amdgcn_global_load_lds(
      (const __attribute__((address_space(1))) void*)g,
      (__attribute__((address_space(3))) void*)l, 16, 0, 0);
}

constexpr int Bz = 8, Sq = 512, Em = 1024, Hn = 16, Dh = 64;
constexpr int Mrows = Bz * Sq;             // 4096
constexpr size_t NE = (size_t)Mrows * Em;  // 4,194,304
constexpr size_t WE = (size_t)Em * Em;     // 1,048,576
constexpr int NT = Em / 64;                // 16 K-tiles

// ---------------- f32 -> bf16 pre-convert (unchanged) ----------------
__global__ __launch_bounds__(256) void convert_kernel(
    const float* __restrict__ q, const float* __restrict__ k,
    const float* __restrict__ v,
    const float* __restrict__ Wq, const float* __restrict__ Wk,
    const float* __restrict__ Wv, const float* __restrict__ Wo,
    short* __restrict__ qx, short* __restrict__ kx, short* __restrict__ vx,
    short* __restrict__ wqb, short* __restrict__ wkb,
    short* __restrict__ wvb, short* __restrict__ wob)
{
  const size_t c = (size_t)blockIdx.x * 256 + threadIdx.x;
  constexpr size_t CI = NE / 8;
  constexpr size_t CW = WE / 8;
  const float* src; short* dst; size_t off;
  if (c < 3 * CI) {
    const int sgi = (int)(c / CI);
    src = sgi == 0 ? q : sgi == 1 ? k : v;
    dst = sgi == 0 ? qx : sgi == 1 ? kx : vx;
    off = (c - (size_t)sgi * CI) * 8;
  } else {
    const size_t w = c - 3 * CI;
    const int sgi = (int)(w / CW);
    src = sgi == 0 ? Wq : sgi == 1 ? Wk : sgi == 2 ? Wv : Wo;
    dst = sgi == 0 ? wqb : sgi == 1 ? wkb : sgi == 2 ? wvb : wob;
    off = (w - (size_t)sgi * CW) * 8;
  }
  fx4 a = *(const fx4*)(src + off);
  fx4 b = *(const fx4*)(src + off + 4);
  bfx8 o = { f2bf(a[0]), f2bf(a[1]), f2bf(a[2]), f2bf(a[3]),
             f2bf(b[0]), f2bf(b[1]), f2bf(b[2]), f2bf(b[3]) };
  *(bfx8*)(dst + off) = o;
}

// ---------------- gemm_qkv: 256x256, 8 waves, 4-phase/K-tile (R11) ----------------
// R12 delta: no wrap-staging on the last K-tile (saves 64KB fetch/block).
__global__ __launch_bounds__(512, 2) void gemm_qkv_bf16(
    const short* __restrict__ qx, const short* __restrict__ kx,
    const short* __restrict__ vx,
    const short* __restrict__ Wqb, const short* __restrict__ Wkb,
    const short* __restrict__ Wvb,
    const float* __restrict__ bq, const float* __restrict__ bk,
    const float* __restrict__ bv,
    const float* __restrict__ pos,
    short* __restrict__ qb, short* __restrict__ kb, short* __restrict__ vb)
{
  __shared__ short SM[65536];   // 128KB

  const int z = blockIdx.z;
  const short* X = (z == 0) ? qx : (z == 1) ? kx : vx;
  const short* W = (z == 0) ? Wqb : (z == 1) ? Wkb : Wvb;
  const float* bias = (z == 0) ? bq : (z == 1) ? bk : bv;
  short* dst = (z == 0) ? qb : (z == 1) ? kb : vb;

  const int t0b = blockIdx.x * 256;
  const int f0 = blockIdx.y * 256;
  const int t = threadIdx.x, lane = t & 63, wave = t >> 6;
  const int wr = wave >> 2;
  const int wn = wave & 3;
  const int fr = lane & 15, fq = lane >> 4;

  const int srow = t >> 3;
  const int scc = (t & 7) ^ (srow & 7);
  const int sdst = wave * 512;

  const int sw0 = (fq ^ (fr & 7)) * 8;
  const int sw1 = ((4 + fq) ^ (fr & 7)) * 8;

  auto stageA = [&](int hh, int ktn, int pn) {
    const short* s = W + (size_t)(f0 + hh * 128 + srow) * Em + ktn * 64 + scc * 8;
    short* d = SM + pn * 32768 + hh * 8192 + sdst;
    gld16(s, d);
    gld16(s + (size_t)64 * Em, d + 4096);
  };
  auto stageB = [&](int hh, int ktn, int pn) {
    const short* s = X + (size_t)(t0b + hh * 128 + srow) * Em + ktn * 64 + scc * 8;
    short* d = SM + pn * 32768 + 16384 + hh * 8192 + sdst;
    gld16(s, d);
    gld16(s + (size_t)64 * Em, d + 4096);
  };

  fx4 acc[8][4] = {};

  stageA(0, 0, 0); stageA(1, 0, 0); stageB(0, 0, 0); stageB(1, 0, 0);
  __builtin_amdgcn_sched_barrier(0);
  asm volatile("s_waitcnt vmcnt(0)");
  __builtin_amdgcn_sched_barrier(0);
  __builtin_amdgcn_s_barrier();

  for (int kt = 0; kt < NT; ++kt) {
    const int p = kt & 1, pn = p ^ 1;
    const bool pre = (kt + 1 < NT);
    const short* Ab = SM + p * 32768 + wr * 8192;
    const short* Bb = SM + p * 32768 + 16384 + (wn >> 1) * 8192 + (wn & 1) * 4096;

    bfx8 bf[4][2];
#pragma unroll
    for (int q = 0; q < 4; ++q) {
      if (q == 0) {
#pragma unroll
        for (int cg = 0; cg < 4; ++cg) {
          bf[cg][0] = *(const bfx8*)&Bb[(cg * 16 + fr) * 64 + sw0];
          bf[cg][1] = *(const bfx8*)&Bb[(cg * 16 + fr) * 64 + sw1];
        }
      }
      bfx8 af[2][2];
#pragma unroll
      for (int rr2 = 0; rr2 < 2; ++rr2) {
        const int row = (q * 2 + rr2) * 16 + fr;
        af[rr2][0] = *(const bfx8*)&Ab[row * 64 + sw0];
        af[rr2][1] = *(const bfx8*)&Ab[row * 64 + sw1];
      }
      if (q == 0 && pre) { stageA(0, kt + 1, pn); stageA(1, kt + 1, pn); }
      if (q == 1 && pre) { stageB(0, kt + 1, pn); stageB(1, kt + 1, pn); }

      __builtin_amdgcn_sched_barrier(0);
      __builtin_amdgcn_s_barrier();
      __builtin_amdgcn_sched_barrier(0);

      __builtin_amdgcn_s_setprio(1);
#pragma unroll
      for (int rr2 = 0; rr2 < 2; ++rr2)
#pragma unroll
        for (int cg = 0; cg < 4; ++cg) {
          acc[q * 2 + rr2][cg] = __builtin_amdgcn_mfma_f32_16x16x32_bf16(
              af[rr2][0], bf[cg][0], acc[q * 2 + rr2][cg], 0, 0, 0);
          acc[q * 2 + rr2][cg] = __builtin_amdgcn_mfma_f32_16x16x32_bf16(
              af[rr2][1], bf[cg][1], acc[q * 2 + rr2][cg], 0, 0, 0);
        }
      __builtin_amdgcn_s_setprio(0);
      __builtin_amdgcn_sched_barrier(0);

      if (q == 3 && pre) {
        asm volatile("s_waitcnt vmcnt(0)");
        __builtin_amdgcn_sched_barrier(0);
      }
      __builtin_amdgcn_s_barrier();
    }
  }

  // ---- epilogue (R11, unchanged) ----
  const int b = t0b >> 9;
  if (z < 2) {
#pragma unroll
    for (int fp = 0; fp < 2; ++fp) {
      if (fp) __syncthreads();
      if (wr == fp) {
#pragma unroll
        for (int rg = 0; rg < 8; ++rg) {
          const int nloc = rg * 16 + fq * 4;
          const int nng = f0 + fp * 128 + nloc;
          const fx4 bb = *(const fx4*)&bias[nng];
#pragma unroll
          for (int cg = 0; cg < 4; ++cg) {
            const int token = wn * 64 + cg * 16 + fr;
            const int s = (t0b + token) & (Sq - 1);
            const fx4 pe = *(const fx4*)&pos[(size_t)s * Em + nng];
            const fx4 a = acc[rg][cg];
            bfx4 o = { f2bf(a[0] + bb[0] + pe[0]), f2bf(a[1] + bb[1] + pe[1]),
                       f2bf(a[2] + bb[2] + pe[2]), f2bf(a[3] + bb[3] + pe[3]) };
            *(bfx4*)&SM[token * 136 + nloc] = o;
          }
        }
      }
      __syncthreads();
#pragma unroll
      for (int it = 0; it < 8; ++it) {
        const int flat = it * 512 + t;
        const int token = flat >> 4, ch = flat & 15;
        bfx8 val = *(const bfx8*)&SM[token * 136 + ch * 8];
        const int nng = f0 + fp * 128 + ch * 8;
        const int h = nng >> 6, d = nng & 63;
        const int s = (t0b + token) & (Sq - 1);
        *(bfx8*)&dst[(((size_t)b * Hn + h) * Sq + s) * Dh + d] = val;
      }
    }
  } else {
#pragma unroll
    for (int fp = 0; fp < 2; ++fp) {
      if (fp) __syncthreads();
      if (wr == fp) {
#pragma unroll
        for (int rg = 0; rg < 8; ++rg) {
          const int nloc = rg * 16 + fq * 4;
          const int nng = f0 + fp * 128 + nloc;
          const fx4 bb = *(const fx4*)&bias[nng];
#pragma unroll
          for (int cg = 0; cg < 4; ++cg) {
            const int token = wn * 64 + cg * 16 + fr;
            const int s = (t0b + token) & (Sq - 1);
            const fx4 pe = *(const fx4*)&pos[(size_t)s * Em + nng];
            const fx4 a = acc[rg][cg];
#pragma unroll
            for (int i = 0; i < 4; ++i)
              SM[(nloc + i) * 264 + token] = f2bf(a[i] + bb[i] + pe[i]);
          }
        }
      }
      __syncthreads();
      const int s0 = t0b & (Sq - 1);
#pragma unroll
      for (int it = 0; it < 8; ++it) {
        const int flat = it * 512 + t;
        const int row = flat >> 5, ch = flat & 31;
        bfx8 val = *(const bfx8*)&SM[row * 264 + ch * 8];
        const int nng = f0 + fp * 128 + row;
        const int h = nng >> 6, d = nng & 63;
        *(bfx8*)&dst[(((size_t)b * Hn + h) * Dh + d) * Sq + s0 + ch * 8] = val;
      }
    }
  }
}

// ---------------- gemm_out (R7/R9 proven, unchanged) ----------------
constexpr int LDP = 136;

__global__ __launch_bounds__(256, 4) void gemm_out_bf16(
    const short* __restrict__ wv, const short* __restrict__ Wob,
    const float* __restrict__ bo, float* __restrict__ out)
{
  __shared__ short SMo[2 * 8192];
  short* As = SMo;
  short* Bs = SMo + 8192;

  const int m0 = blockIdx.x * 128;
  const int n0 = blockIdx.y * 128;
  const int t = threadIdx.x, lane = t & 63, wave = t >> 6;
  const int wr = wave >> 1, wc = wave & 1;
  const int fr = lane & 15, fq = lane >> 4;

  const int trow = t >> 3;
  const int scol = ((t & 7) ^ (trow & 7)) * 8;
  const short* gW = Wob + (size_t)(n0 + trow) * Em + scol;
  const short* gX = wv + (size_t)(m0 + trow) * Em + scol;
  short* lA = As + wave * 512;
  short* lB = Bs + wave * 512;

  const int sw0 = ((fq ^ (fr & 7)) * 8);
  const int sw1 = (((4 + fq) ^ (fr & 7)) * 8);

  fx4 acc[4][4] = {};

  for (int k0 = 0; k0 < Em; k0 += 64) {
#pragma unroll
    for (int r = 0; r < 4; ++r) {
      gld16(gW + (size_t)(32 * r) * Em + k0, lA + r * 2048);
      gld16(gX + (size_t)(32 * r) * Em + k0, lB + r * 2048);
    }
    __syncthreads();

#pragma unroll
    for (int ks = 0; ks < 2; ++ks) {
      const int sw = ks ? sw1 : sw0;
      bfx8 af[4], bf[4];
#pragma unroll
      for (int u = 0; u < 4; ++u)
        af[u] = *(const bfx8*)&As[(wr * 64 + u * 16 + fr) * 64 + sw];
#pragma unroll
      for (int v = 0; v < 4; ++v)
        bf[v] = *(const bfx8*)&Bs[(wc * 64 + v * 16 + fr) * 64 + sw];
#pragma unroll
      for (int u = 0; u < 4; ++u)
#pragma unroll
        for (int v = 0; v < 4; ++v)
          acc[u][v] = __builtin_amdgcn_mfma_f32_16x16x32_bf16(af[u], bf[v], acc[u][v], 0, 0, 0);
    }
    __syncthreads();
  }

#pragma unroll
  for (int u = 0; u < 4; ++u) {
    const int nn = n0 + wr * 64 + u * 16 + fq * 4;
    const fx4 bb = *(const fx4*)&bo[nn];
#pragma unroll
    for (int v = 0; v < 4; ++v) {
      const int m = m0 + wc * 64 + v * 16 + fr;
      fx4 val = acc[u][v];
      val[0] += bb[0]; val[1] += bb[1]; val[2] += bb[2]; val[3] += bb[3];
      *(fx4*)&out[(size_t)m * Em + nn] = val;
    }
  }
}

// ---------------- Attention: QBLK=128 (8 waves), T14 + T13 defer-max + T5 ----------------
// Each staged K/V tile now feeds 8 waves (2x amortization). Staging: 1 bfx8
// chunk per thread for K and V each. Per-wave softmax/PV unchanged from R9.
constexpr int KVB = 64, LDK = 72;

__global__ __launch_bounds__(512) void attn_kernel(
    const short* __restrict__ qb, const short* __restrict__ kb,
    const short* __restrict__ vb, short* __restrict__ wv)
{
  __shared__ short Ks[KVB * LDK];
  __shared__ short Vt[Dh * LDK];
  __shared__ short Ps[8][16 * LDK];

  const int bh = blockIdx.x;
  const int qt = blockIdx.y;         // q tile of 128
  const int t = threadIdx.x, lane = t & 63, wave = t >> 6;
  const int fr = lane & 15, fq = lane >> 4;

  const size_t base = (size_t)bh * Sq * Dh;
  const int q0 = qt * 128 + wave * 16;

  bfx8 qf[2];
  {
    const short* qp = qb + base + (size_t)(q0 + fr) * Dh;
    qf[0] = *(const bfx8*)(qp + fq * 8);
    qf[1] = *(const bfx8*)(qp + 32 + fq * 8);
  }

  // staging: thread t -> row t>>3 (0..63), col chunk (t&7)*8; one bfx8 each
  const int kr = t >> 3, kc = (t & 7) * 8;
  const short* kbp = kb + base + (size_t)kr * Dh + kc;   // + kv0*Dh
  const short* vbp = vb + base + (size_t)kr * Sq + kc;   // + kv0

  {
    bfx8 k0 = *(const bfx8*)kbp;
    bfx8 v0 = *(const bfx8*)vbp;
    *(bfx8*)&Ks[kr * LDK + kc] = k0;
    *(bfx8*)&Vt[kr * LDK + kc] = v0;
  }
  __syncthreads();

  float mrow[4] = { -1e30f, -1e30f, -1e30f, -1e30f };
  float lrow[4] = { 0.f, 0.f, 0.f, 0.f };
  fx4 oacc[4] = {};

  for (int kv0 = 0; kv0 < Sq; kv0 += KVB) {
    const bool more = (kv0 + KVB) < Sq;
    bfx8 nk0, nv0;
    if (more) {   // T14: issue next tile's loads now
      nk0 = *(const bfx8*)(kbp + (size_t)(kv0 + KVB) * Dh);
      nv0 = *(const bfx8*)(vbp + kv0 + KVB);
    }

    // S = Q K^T
    fx4 sa[4] = {};
    __builtin_amdgcn_s_setprio(1);
#pragma unroll
    for (int nf = 0; nf < 4; ++nf) {
#pragma unroll
      for (int ks = 0; ks < 2; ++ks) {
        bfx8 kf = *(const bfx8*)&Ks[(nf * 16 + fr) * LDK + ks * 32 + fq * 8];
        sa[nf] = __builtin_amdgcn_mfma_f32_16x16x32_bf16(qf[ks], kf, sa[nf], 0, 0, 0);
      }
    }
    __builtin_amdgcn_s_setprio(0);

    // online softmax with T13 defer-max (THR=8)
#pragma unroll
    for (int i = 0; i < 4; ++i) {
      float mx = fmaxf(fmaxf(sa[0][i], sa[1][i]), fmaxf(sa[2][i], sa[3][i]));
      mx = fmaxf(mx, __shfl_xor(mx, 1));
      mx = fmaxf(mx, __shfl_xor(mx, 2));
      mx = fmaxf(mx, __shfl_xor(mx, 4));
      mx = fmaxf(mx, __shfl_xor(mx, 8));
      mx *= 0.125f;
      if (mx > mrow[i] + 8.f) {     // group-uniform branch
        const float alpha = __expf(mrow[i] - mx);
        mrow[i] = mx;
        lrow[i] *= alpha;
#pragma unroll
        for (int df = 0; df < 4; ++df) oacc[df][i] *= alpha;
      }
      float rs = 0.f;
#pragma unroll
      for (int nf = 0; nf < 4; ++nf) {
        const float p = __expf(sa[nf][i] * 0.125f - mrow[i]);
        rs += p;
        Ps[wave][(fq * 4 + i) * LDK + nf * 16 + fr] = f2bf(p);
      }
      rs += __shfl_xor(rs, 1);
      rs += __shfl_xor(rs, 2);
      rs += __shfl_xor(rs, 4);
      rs += __shfl_xor(rs, 8);
      lrow[i] += rs;
    }

    // O += P @ V
    bfx8 pf[2];
    pf[0] = *(const bfx8*)&Ps[wave][fr * LDK + fq * 8];
    pf[1] = *(const bfx8*)&Ps[wave][fr * LDK + 32 + fq * 8];
    __builtin_amdgcn_s_setprio(1);
#pragma unroll
    for (int df = 0; df < 4; ++df) {
#pragma unroll
      for (int ks = 0; ks < 2; ++ks) {
        bfx8 vf = *(const bfx8*)&Vt[(df * 16 + fr) * LDK + ks * 32 + fq * 8];
        oacc[df] = __builtin_amdgcn_mfma_f32_16x16x32_bf16(pf[ks], vf, oacc[df], 0, 0, 0);
      }
    }
    __builtin_amdgcn_s_setprio(0);
    __syncthreads();   // all waves done reading Ks/Vt

    if (more) {        // write prefetched tile
      *(bfx8*)&Ks[kr * LDK + kc] = nk0;
      *(bfx8*)&Vt[kr * LDK + kc] = nv0;
      __syncthreads();
    }
  }

  const int b = bh >> 4, h = bh & 15;
#pragma unroll
  for (int df = 0; df < 4; ++df) {
    const int d = df * 16 + fr;
#pragma unroll
    for (int i = 0; i < 4; ++i) {
      const int qrow = q0 + fq * 4 + i;
      const float o = oacc[df][i] / lrow[i];
      wv[((size_t)b * Sq + qrow) * Em + h * Dh + d] = f2bf(o);
    }
  }
}

extern "C" void kernel_launch(void* const* d_in, const int* in_sizes, int n_in,
                              void* d_out, int out_size, void* d_ws, size_t ws_size,
                              hipStream_t stream) {
  (void)in_sizes; (void)n_in; (void)out_size; (void)ws_size;
  const float* query = (const float*)d_in[0];
  const float* key   = (const float*)d_in[1];
  const float* value = (const float*)d_in[2];
  const float* Wq = (const float*)d_in[3];
  const float* bq = (const float*)d_in[4];
  const float* Wk = (const float*)d_in[5];
  const float* bk = (const float*)d_in[6];
  const float* Wv = (const float*)d_in[7];
  const float* bv = (const float*)d_in[8];
  const float* Wo = (const float*)d_in[9];
  const float* bo = (const float*)d_in[10];
  const float* pos = (const float*)d_in[11];

  short* qx = (short*)d_ws;
  short* kx = qx + NE;
  short* vx = kx + NE;
  short* Wqb = vx + NE;
  short* Wkb = Wqb + WE;
  short* Wvb = Wkb + WE;
  short* Wob = Wvb + WE;
  short* qb = Wob + WE;
  short* wv = qx;                 // alias: qx dead after gemm_qkv
  short* kb = (short*)d_out;      // d_out scratch, overwritten by gemm_out
  short* vb = kb + NE;            // [B,H,Dh,S]

  convert_kernel<<<dim3(8192), 256, 0, stream>>>(
      query, key, value, Wq, Wk, Wv, Wo, qx, kx, vx, Wqb, Wkb, Wvb, Wob);
  gemm_qkv_bf16<<<dim3(Mrows / 256, Em / 256, 3), 512, 0, stream>>>(
      qx, kx, vx, Wqb, Wkb, Wvb, bq, bk, bv, pos, qb, kb, vb);
  attn_kernel<<<dim3(Bz * Hn, Sq / 128), 512, 0, stream>>>(qb, kb, vb, wv);
  gemm_out_bf16<<<dim3(Mrows / 128, Em / 128), 256, 0, stream>>>(
      wv, Wob, bo, (float*)d_out);
}